// Round 1
// baseline (817.467 us; speedup 1.0000x reference)
//
#include <hip/hip_runtime.h>
#include <cstdint>
#include <cstddef>

typedef unsigned short u16;
typedef short bf16x8 __attribute__((ext_vector_type(8)));
typedef float f32x4 __attribute__((ext_vector_type(4)));

constexpr int B_ = 4, T_ = 1024, E_ = 1024, H_ = 16, D_ = 64;

__device__ __forceinline__ float bf2f(u16 u) {
  union { unsigned u; float f; } v; v.u = ((unsigned)u) << 16; return v.f;
}
__device__ __forceinline__ u16 f2bf(float f) {
  union { float f; unsigned u; } v; v.f = f;
  return (u16)((v.u + 0x7fffu + ((v.u >> 16) & 1u)) >> 16);
}

#define GLD_LDS16(gp, lp)                                                      \
  __builtin_amdgcn_global_load_lds(                                            \
      (const __attribute__((address_space(1))) void*)(gp),                     \
      (__attribute__((address_space(3))) void*)(lp), 16, 0, 0)

// ---------------------------------------------------------------------------
// Tiled bf16 MFMA GEMM, C = alpha * A @ B^T.
// A: (M,K) bf16 row-major, row stride lda. B: (N,K) bf16 row-major ("BT").
// Optional split-bf16 (hi/lo) operands for ~fp32-accurate product (SPLIT).
// Batched via blockIdx.z with element strides batchA/batchB/batchC.
// m97 structure: 128-wide tiles, BK=32, global_load_lds width 16, 16x16x32 MFMA.
// ---------------------------------------------------------------------------
template<int WM, int WN, int MT, int NT, bool SPLIT, bool CBF16>
__global__ __launch_bounds__(WM * WN * 64) void gemm_bt(
    const u16* __restrict__ A, const u16* __restrict__ Alo,
    const u16* __restrict__ Bm, const u16* __restrict__ Blo,
    void* __restrict__ Cv, int N, int K,
    int lda, int ldb, int ldc,
    long batchA, long batchB, long batchC, float alpha)
{
  constexpr int TM = WM * MT * 16;
  constexpr int TN = WN * NT * 16;
  constexpr int THREADS = WM * WN * 64;
  constexpr int ASZ = TM * 32, BSZ = TN * 32;

  __shared__ u16 smem[(SPLIT ? 2 : 1) * (ASZ + BSZ)];
  u16* sA  = smem;
  u16* sB  = smem + ASZ;
  u16* sAl = smem + ASZ + BSZ;
  u16* sBl = smem + 2 * ASZ + BSZ;

  const int z = blockIdx.z;
  const u16* Ab = A + (size_t)z * batchA;
  const u16* Bb = Bm + (size_t)z * batchB;
  const int m0 = blockIdx.y * TM;
  const int n0 = blockIdx.x * TN;
  const int tid = threadIdx.x;
  const int lane = tid & 63;
  const int wave = tid >> 6;
  const int wm = wave % WM;
  const int wn = wave / WM;
  const int fr = lane & 15;   // row within 16x16 frag
  const int fg = lane >> 4;   // k-chunk (8 bf16 each)

  f32x4 acc[MT][NT];
  const f32x4 zero = {0.f, 0.f, 0.f, 0.f};
  #pragma unroll
  for (int i = 0; i < MT; i++) {
    #pragma unroll
    for (int j = 0; j < NT; j++) acc[i][j] = zero;
  }

  for (int k0 = 0; k0 < K; k0 += 32) {
    __syncthreads();   // previous tile fully consumed
    for (int s = tid; s < TM * 4; s += THREADS) {
      const int row = s >> 2, ch = s & 3;
      const size_t go = (size_t)(m0 + row) * lda + k0 + ch * 8;
      GLD_LDS16(Ab + go, &sA[s * 8]);
      if constexpr (SPLIT) GLD_LDS16(Alo + (size_t)z * batchA + go, &sAl[s * 8]);
    }
    for (int s = tid; s < TN * 4; s += THREADS) {
      const int row = s >> 2, ch = s & 3;
      int rr = n0 + row; if (rr > N - 1) rr = N - 1;  // clamp (epilogue masks cols >= N)
      const size_t go = (size_t)rr * ldb + k0 + ch * 8;
      GLD_LDS16(Bb + go, &sB[s * 8]);
      if constexpr (SPLIT) GLD_LDS16(Blo + (size_t)z * batchB + go, &sBl[s * 8]);
    }
    __syncthreads();   // drains vmcnt(0) before barrier (m97 semantics)

    bf16x8 av[MT], bv[NT];
    #pragma unroll
    for (int mt = 0; mt < MT; mt++)
      av[mt] = *(const bf16x8*)&sA[((wm * MT + mt) * 16 + fr) * 32 + fg * 8];
    #pragma unroll
    for (int nt = 0; nt < NT; nt++)
      bv[nt] = *(const bf16x8*)&sB[((wn * NT + nt) * 16 + fr) * 32 + fg * 8];
    #pragma unroll
    for (int mt = 0; mt < MT; mt++) {
      #pragma unroll
      for (int nt = 0; nt < NT; nt++)
        acc[mt][nt] = __builtin_amdgcn_mfma_f32_16x16x32_bf16(av[mt], bv[nt], acc[mt][nt], 0, 0, 0);
    }
    if constexpr (SPLIT) {
      bf16x8 al[MT], bl[NT];
      #pragma unroll
      for (int mt = 0; mt < MT; mt++)
        al[mt] = *(const bf16x8*)&sAl[((wm * MT + mt) * 16 + fr) * 32 + fg * 8];
      #pragma unroll
      for (int nt = 0; nt < NT; nt++)
        bl[nt] = *(const bf16x8*)&sBl[((wn * NT + nt) * 16 + fr) * 32 + fg * 8];
      #pragma unroll
      for (int mt = 0; mt < MT; mt++) {
        #pragma unroll
        for (int nt = 0; nt < NT; nt++) {
          acc[mt][nt] = __builtin_amdgcn_mfma_f32_16x16x32_bf16(al[mt], bv[nt], acc[mt][nt], 0, 0, 0);
          acc[mt][nt] = __builtin_amdgcn_mfma_f32_16x16x32_bf16(av[mt], bl[nt], acc[mt][nt], 0, 0, 0);
        }
      }
    }
  }

  // epilogue: C/D layout col = lane&15, row = (lane>>4)*4 + reg (m89-verified)
  const int er = (lane >> 4) * 4;
  const int ec = lane & 15;
  #pragma unroll
  for (int mt = 0; mt < MT; mt++) {
    #pragma unroll
    for (int nt = 0; nt < NT; nt++) {
      const int row = m0 + (wm * MT + mt) * 16 + er;
      const int col = n0 + (wn * NT + nt) * 16 + ec;
      if (col < N) {
        #pragma unroll
        for (int r2 = 0; r2 < 4; r2++) {
          const float vv = acc[mt][nt][r2] * alpha;
          const size_t ci = (size_t)z * batchC + (size_t)(row + r2) * ldc + col;
          if constexpr (CBF16) ((u16*)Cv)[ci] = f2bf(vv);
          else                 ((float*)Cv)[ci] = vv;
        }
      }
    }
  }
}

// ---------------------------------------------------------------------------
// Reductions (256-thread blocks, 4 waves)
// ---------------------------------------------------------------------------
__device__ __forceinline__ float block_max256(float v, float* red) {
  #pragma unroll
  for (int m = 32; m > 0; m >>= 1) v = fmaxf(v, __shfl_xor(v, m, 64));
  if ((threadIdx.x & 63) == 0) red[threadIdx.x >> 6] = v;
  __syncthreads();
  const float r = fmaxf(fmaxf(red[0], red[1]), fmaxf(red[2], red[3]));
  __syncthreads();
  return r;
}
__device__ __forceinline__ float block_sum256(float v, float* red) {
  #pragma unroll
  for (int m = 32; m > 0; m >>= 1) v += __shfl_xor(v, m, 64);
  if ((threadIdx.x & 63) == 0) red[threadIdx.x >> 6] = v;
  __syncthreads();
  const float r = (red[0] + red[1]) + (red[2] + red[3]);
  __syncthreads();
  return r;
}

// ---------------------------------------------------------------------------
// Casts
// ---------------------------------------------------------------------------
__global__ __launch_bounds__(256) void cast_bf16(const float* __restrict__ in, u16* __restrict__ out) {
  const size_t i = ((size_t)blockIdx.x * 256 + threadIdx.x) * 4;
  const float4 v = *(const float4*)(in + i);
  ushort4 o;
  o.x = f2bf(v.x); o.y = f2bf(v.y); o.z = f2bf(v.z); o.w = f2bf(v.w);
  *(ushort4*)(out + i) = o;
}
__global__ __launch_bounds__(256) void cast_split(const float* __restrict__ in,
                                                  u16* __restrict__ hi, u16* __restrict__ lo) {
  const size_t i = ((size_t)blockIdx.x * 256 + threadIdx.x) * 4;
  const float4 v = *(const float4*)(in + i);
  ushort4 oh, ol;
  oh.x = f2bf(v.x); ol.x = f2bf(v.x - bf2f(oh.x));
  oh.y = f2bf(v.y); ol.y = f2bf(v.y - bf2f(oh.y));
  oh.z = f2bf(v.z); ol.z = f2bf(v.z - bf2f(oh.z));
  oh.w = f2bf(v.w); ol.w = f2bf(v.w - bf2f(oh.w));
  *(ushort4*)(hi + i) = oh;
  *(ushort4*)(lo + i) = ol;
}

// ---------------------------------------------------------------------------
// sc[b,t] = ||echo[b,t,:]||^2 / 32   (echo_back GEMM eliminated algebraically)
// ---------------------------------------------------------------------------
__global__ __launch_bounds__(256) void sc_kernel(const float* __restrict__ echo, float* __restrict__ sc) {
  const int row = blockIdx.x;
  const float4 v = ((const float4*)(echo + (size_t)row * E_))[threadIdx.x];
  float ss = v.x * v.x + v.y * v.y + v.z * v.z + v.w * v.w;
  __shared__ float red[4];
  ss = block_sum256(ss, red);
  if (threadIdx.x == 0) sc[row] = ss * (1.0f / 32.0f);
}

// ---------------------------------------------------------------------------
// s2[b,h,t] = dot(x[b,t,:], wr[h,:,t]) / 8
// ---------------------------------------------------------------------------
__global__ __launch_bounds__(256) void s2_kernel(
    const float* __restrict__ x, const float* __restrict__ wr, float* __restrict__ s2) {
  const int t = blockIdx.x * 256 + threadIdx.x;
  const int h = blockIdx.y, b = blockIdx.z;
  const float* xr = x + ((size_t)b * T_ + t) * E_;
  const float* wc = wr + (size_t)h * E_ * T_ + t;
  float acc = 0.f;
  #pragma unroll 8
  for (int e = 0; e < E_; e++) acc += xr[e] * wc[(size_t)e * T_];
  s2[((size_t)b * H_ + h) * T_ + t] = acc * 0.125f;
}

// ---------------------------------------------------------------------------
// In-place causal softmax over bf16 score rows (per b slab: layout h,i,j)
// ---------------------------------------------------------------------------
__global__ __launch_bounds__(256) void softmax_causal(u16* __restrict__ S) {
  const int i = blockIdx.x;
  const int h = blockIdx.y;
  u16* row = S + ((size_t)h * T_ + i) * T_;
  __shared__ float red[4];
  float v[4];
  float m = -3.0e38f;
  #pragma unroll
  for (int k = 0; k < 4; k++) {
    const int j = threadIdx.x + k * 256;
    const float xv = (j <= i) ? bf2f(row[j]) : -3.0e38f;
    v[k] = xv;
    m = fmaxf(m, xv);
  }
  m = block_max256(m, red);
  float s = 0.f;
  #pragma unroll
  for (int k = 0; k < 4; k++) {
    const int j = threadIdx.x + k * 256;
    const float p = (j <= i) ? __expf(v[k] - m) : 0.f;
    v[k] = p;
    s += p;
  }
  s = block_sum256(s, red);
  const float inv = 1.0f / s;
  #pragma unroll
  for (int k = 0; k < 4; k++) {
    const int j = threadIdx.x + k * 256;
    row[j] = f2bf(v[k] * inv);
  }
}

// ---------------------------------------------------------------------------
// a3[b,i,j] = softmax_{j<=i}(sc_i*sc_j), written bf16 (zeros above diagonal)
// ---------------------------------------------------------------------------
__global__ __launch_bounds__(256) void a3_softmax(const float* __restrict__ sc, u16* __restrict__ a3) {
  const int i = blockIdx.x;
  const int b = blockIdx.y;
  const float* sr = sc + (size_t)b * T_;
  const float sci = sr[i];
  u16* row = a3 + ((size_t)b * T_ + i) * T_;
  __shared__ float red[4];
  float v[4];
  float m = -3.0e38f;
  #pragma unroll
  for (int k = 0; k < 4; k++) {
    const int j = threadIdx.x + k * 256;
    const float xv = (j <= i) ? sci * sr[j] : -3.0e38f;
    v[k] = xv;
    m = fmaxf(m, xv);
  }
  m = block_max256(m, red);
  float s = 0.f;
  #pragma unroll
  for (int k = 0; k < 4; k++) {
    const int j = threadIdx.x + k * 256;
    const float p = (j <= i) ? __expf(v[k] - m) : 0.f;
    v[k] = p;
    s += p;
  }
  s = block_sum256(s, red);
  const float inv = 1.0f / s;
  #pragma unroll
  for (int k = 0; k < 4; k++) {
    const int j = threadIdx.x + k * 256;
    row[j] = f2bf(v[k] * inv);
  }
}

// ---------------------------------------------------------------------------
// Branch 2: broadcast-key softmax => prefix scan. One wave per (b,h), lane=d.
// ---------------------------------------------------------------------------
__global__ __launch_bounds__(64) void branch2_scan(
    const float* __restrict__ s2, const u16* __restrict__ rv, u16* __restrict__ out2) {
  const int h = blockIdx.x, b = blockIdx.y;
  const int d = threadIdx.x;
  const float* srow = s2 + ((size_t)b * H_ + h) * T_;
  float m = -3.0e38f;
  for (int j = d; j < T_; j += 64) m = fmaxf(m, srow[j]);
  #pragma unroll
  for (int mk = 32; mk > 0; mk >>= 1) m = fmaxf(m, __shfl_xor(m, mk, 64));
  const u16* rvp = rv + (size_t)b * T_ * E_ + h * D_ + d;
  u16* op = out2 + (size_t)b * T_ * E_ + h * D_ + d;
  float num = 0.f, den = 0.f;
  for (int j = 0; j < T_; j++) {
    const float w = __expf(srow[j] - m);
    den += w;
    num += w * bf2f(rvp[(size_t)j * E_]);
    op[(size_t)j * E_] = f2bf(num / den);
  }
}

// ---------------------------------------------------------------------------
// Transposes
// ---------------------------------------------------------------------------
__global__ __launch_bounds__(256) void transpose_v(const u16* __restrict__ v, u16* __restrict__ vT) {
  // v: (B,T,H*D) -> vT: (B,H,D,T); grid (B*H, D/32, T/32)
  const int bh = blockIdx.x;
  const int b = bh >> 4, h = bh & 15;
  const int d0 = blockIdx.y * 32, t0 = blockIdx.z * 32;
  __shared__ u16 tile[32][33];
  const int c = threadIdx.x & 31, r0 = threadIdx.x >> 5;
  #pragma unroll
  for (int rr = 0; rr < 32; rr += 8) {
    const int t = t0 + r0 + rr;
    tile[r0 + rr][c] = v[((size_t)b * T_ + t) * E_ + h * 64 + d0 + c];
  }
  __syncthreads();
  #pragma unroll
  for (int rr = 0; rr < 32; rr += 8) {
    const int d = d0 + r0 + rr;
    vT[((size_t)bh * D_ + d) * T_ + t0 + c] = tile[c][r0 + rr];
  }
}

__global__ __launch_bounds__(256) void transpose_echo(const float* __restrict__ e, u16* __restrict__ eT) {
  // e: (B,T,E) f32 -> eT: (B,E,T) bf16; grid (B, E/32, T/32)
  const int b = blockIdx.x;
  const int f0 = blockIdx.y * 32, t0 = blockIdx.z * 32;
  __shared__ float tile[32][33];
  const int c = threadIdx.x & 31, r0 = threadIdx.x >> 5;
  #pragma unroll
  for (int rr = 0; rr < 32; rr += 8) {
    const int t = t0 + r0 + rr;
    tile[r0 + rr][c] = e[((size_t)b * T_ + t) * E_ + f0 + c];
  }
  __syncthreads();
  #pragma unroll
  for (int rr = 0; rr < 32; rr += 8) {
    const int f = f0 + r0 + rr;
    eT[((size_t)b * E_ + f) * T_ + t0 + c] = f2bf(tile[c][r0 + rr]);
  }
}

// ---------------------------------------------------------------------------
// Gated combine: comb = g0*out1 + g1*out2 + g2*out3, g = softmax(gate[h,:])
// ---------------------------------------------------------------------------
__global__ __launch_bounds__(256) void combine_gate(
    const u16* __restrict__ o1, const u16* __restrict__ o2, const u16* __restrict__ o3,
    const float* __restrict__ gate, u16* __restrict__ comb) {
  const size_t idx = (size_t)blockIdx.x * 256 + threadIdx.x;
  const int f = (int)(idx & (E_ - 1));
  const int h = f >> 6;
  const float g0 = gate[h * 3 + 0], g1 = gate[h * 3 + 1], g2 = gate[h * 3 + 2];
  const float mx = fmaxf(g0, fmaxf(g1, g2));
  const float e0 = __expf(g0 - mx), e1 = __expf(g1 - mx), e2 = __expf(g2 - mx);
  const float inv = 1.0f / (e0 + e1 + e2);
  const float o = (e0 * bf2f(o1[idx]) + e1 * bf2f(o2[idx]) + e2 * bf2f(o3[idx])) * inv;
  comb[idx] = f2bf(o);
}

// ---------------------------------------------------------------------------
extern "C" void kernel_launch(void* const* d_in, const int* in_sizes, int n_in,
                              void* d_out, int out_size, void* d_ws, size_t ws_size,
                              hipStream_t stream) {
  (void)in_sizes; (void)n_in; (void)out_size; (void)ws_size;
  const float* x    = (const float*)d_in[0];
  const float* wq   = (const float*)d_in[1];
  const float* wk   = (const float*)d_in[2];
  const float* wv   = (const float*)d_in[3];
  const float* wvr  = (const float*)d_in[4];
  const float* wr   = (const float*)d_in[5];
  const float* wj   = (const float*)d_in[6];
  const float* gate = (const float*)d_in[7];
  const float* wo   = (const float*)d_in[8];
  float* out = (float*)d_out;

  char* p = (char*)d_ws;
  auto alloc = [&](size_t bytes) -> char* {
    char* r = p; p += (bytes + 255) & ~(size_t)255; return r;
  };
  const size_t NTE = (size_t)B_ * T_ * E_;   // 4M elements
  const size_t NW  = (size_t)E_ * E_;        // 1M elements

  u16* xb    = (u16*)alloc(NTE * 2);
  u16* xlo   = (u16*)alloc(NTE * 2);
  u16* wqb   = (u16*)alloc(NW * 2);
  u16* wkb   = (u16*)alloc(NW * 2);
  u16* wvb   = (u16*)alloc(NW * 2);
  u16* wvrb  = (u16*)alloc(NW * 2);
  u16* wjb   = (u16*)alloc(NW * 2);
  u16* wjlo  = (u16*)alloc(NW * 2);
  u16* wob   = (u16*)alloc(NW * 2);
  u16* qb    = (u16*)alloc(NTE * 2);
  u16* kb    = (u16*)alloc(NTE * 2);
  u16* vb    = (u16*)alloc(NTE * 2);
  u16* rvb   = (u16*)alloc(NTE * 2);
  u16* vT    = (u16*)alloc(NTE * 2);
  float* echoF = (float*)alloc(NTE * 4);
  u16* echoT = (u16*)alloc(NTE * 2);
  u16* a3p   = (u16*)alloc(NTE * 2);
  float* sc  = (float*)alloc((size_t)B_ * T_ * 4);
  float* s2  = (float*)alloc((size_t)B_ * H_ * T_ * 4);
  u16* out1b = (u16*)alloc(NTE * 2);
  u16* out2b = (u16*)alloc(NTE * 2);
  u16* out3b = (u16*)alloc(NTE * 2);
  u16* comb  = (u16*)alloc(NTE * 2);
  u16* s1buf = (u16*)alloc((size_t)H_ * T_ * T_ * 2);  // per-b slab, 32 MB

  // ---- casts ----
  cast_split<<<dim3((unsigned)(NTE / 1024)), 256, 0, stream>>>(x, xb, xlo);
  cast_bf16 <<<dim3((unsigned)(NW / 1024)), 256, 0, stream>>>(wq, wqb);
  cast_bf16 <<<dim3((unsigned)(NW / 1024)), 256, 0, stream>>>(wk, wkb);
  cast_bf16 <<<dim3((unsigned)(NW / 1024)), 256, 0, stream>>>(wv, wvb);
  cast_bf16 <<<dim3((unsigned)(NW / 1024)), 256, 0, stream>>>(wvr, wvrb);
  cast_bf16 <<<dim3((unsigned)(NW / 1024)), 256, 0, stream>>>(wo, wob);
  cast_split<<<dim3((unsigned)(NW / 1024)), 256, 0, stream>>>(wj, wjb, wjlo);

  // ---- projections: (B*T,E) @ W^T ----
  const dim3 gproj(E_ / 128, (B_ * T_) / 128, 1);
  gemm_bt<2,2,4,4,false,true><<<gproj, 256, 0, stream>>>(
      xb, nullptr, wqb, nullptr, qb, E_, E_, E_, E_, E_, 0L, 0L, 0L, 1.f);
  gemm_bt<2,2,4,4,false,true><<<gproj, 256, 0, stream>>>(
      xb, nullptr, wkb, nullptr, kb, E_, E_, E_, E_, E_, 0L, 0L, 0L, 1.f);
  gemm_bt<2,2,4,4,false,true><<<gproj, 256, 0, stream>>>(
      xb, nullptr, wvb, nullptr, vb, E_, E_, E_, E_, E_, 0L, 0L, 0L, 1.f);
  gemm_bt<2,2,4,4,false,true><<<gproj, 256, 0, stream>>>(
      xb, nullptr, wvrb, nullptr, rvb, E_, E_, E_, E_, E_, 0L, 0L, 0L, 1.f);
  // echo in split-bf16 (fp32-class accuracy; feeds sc = ||echo||^2/32)
  gemm_bt<2,2,4,4,true,false><<<gproj, 256, 0, stream>>>(
      xb, xlo, wjb, wjlo, echoF, E_, E_, E_, E_, E_, 0L, 0L, 0L, 1.f);

  // ---- small/side computations ----
  transpose_v<<<dim3(B_ * H_, D_ / 32, T_ / 32), 256, 0, stream>>>(vb, vT);
  sc_kernel<<<dim3(B_ * T_), 256, 0, stream>>>(echoF, sc);
  transpose_echo<<<dim3(B_, E_ / 32, T_ / 32), 256, 0, stream>>>(echoF, echoT);
  s2_kernel<<<dim3(T_ / 256, H_, B_), 256, 0, stream>>>(x, wr, s2);

  // ---- branch 2: prefix scan ----
  branch2_scan<<<dim3(H_, B_), 64, 0, stream>>>(s2, rvb, out2b);

  // ---- branch 3: a3 softmax + batched GEMM out3 = a3 @ echo ----
  a3_softmax<<<dim3(T_, B_), 256, 0, stream>>>(sc, a3p);
  gemm_bt<2,2,4,4,false,true><<<dim3(E_ / 128, T_ / 128, B_), 256, 0, stream>>>(
      a3p, nullptr, echoT, nullptr, out3b, E_, T_, T_, T_, E_,
      (long)T_ * T_, (long)E_ * T_, (long)T_ * E_, 1.f);

  // ---- branch 1: per-b materialized scores (s1buf reused across b) ----
  for (int b = 0; b < B_; b++) {
    const size_t bTE = (size_t)b * T_ * E_;
    // s1[h,i,j] = q . k / 8   (batch over h via z; A,B col-offset h*64)
    gemm_bt<2,2,4,4,false,true><<<dim3(T_ / 128, T_ / 128, H_), 256, 0, stream>>>(
        qb + bTE, nullptr, kb + bTE, nullptr, s1buf, T_, D_, E_, E_, T_,
        64L, 64L, (long)T_ * T_, 0.125f);
    softmax_causal<<<dim3(T_, H_), 256, 0, stream>>>(s1buf);
    // out1[b,i,h*64+d] = a1 @ v   (N=64 narrow config)
    gemm_bt<4,1,2,4,false,true><<<dim3(1, T_ / 128, H_), 256, 0, stream>>>(
        s1buf, nullptr, vT + (size_t)b * H_ * D_ * T_, nullptr, out1b + bTE,
        D_, T_, T_, T_, E_, (long)T_ * T_, (long)D_ * T_, 64L, 1.f);
  }

  // ---- combine + output projection ----
  combine_gate<<<dim3((unsigned)(NTE / 256)), 256, 0, stream>>>(out1b, out2b, out3b, gate, comb);
  gemm_bt<2,2,4,4,false,false><<<gproj, 256, 0, stream>>>(
      comb, nullptr, wob, nullptr, out, E_, E_, E_, E_, E_, 0L, 0L, 0L, 1.f);
}

// Round 2
// 728.957 us; speedup vs baseline: 1.1214x; 1.1214x over previous
//
#include <hip/hip_runtime.h>
#include <cstdint>
#include <cstddef>

typedef unsigned short u16;
typedef short bf16x8 __attribute__((ext_vector_type(8)));
typedef float f32x4 __attribute__((ext_vector_type(4)));

constexpr int B_ = 4, T_ = 1024, E_ = 1024, H_ = 16, D_ = 64;

__device__ __forceinline__ float bf2f(u16 u) {
  union { unsigned u; float f; } v; v.u = ((unsigned)u) << 16; return v.f;
}
__device__ __forceinline__ u16 f2bf(float f) {
  union { float f; unsigned u; } v; v.f = f;
  return (u16)((v.u + 0x7fffu + ((v.u >> 16) & 1u)) >> 16);
}

#define GLD_LDS16(gp, lp)                                                      \
  __builtin_amdgcn_global_load_lds(                                            \
      (const __attribute__((address_space(1))) void*)(gp),                     \
      (__attribute__((address_space(3))) void*)(lp), 16, 0, 0)

// ---------------------------------------------------------------------------
// Tiled bf16 MFMA GEMM, C = alpha * A @ B^T.
// A: (M,K) bf16 row-major, row stride lda. B: (N,K) bf16 row-major ("BT").
// Optional split-bf16 (hi/lo) operands for ~fp32-accurate product (SPLIT).
// Batched via blockIdx.z with element strides batchA/batchB/batchC.
// m97 structure: 128-wide tiles, BK=32, global_load_lds width 16, 16x16x32 MFMA.
// ---------------------------------------------------------------------------
template<int WM, int WN, int MT, int NT, bool SPLIT, bool CBF16>
__global__ __launch_bounds__(WM * WN * 64) void gemm_bt(
    const u16* __restrict__ A, const u16* __restrict__ Alo,
    const u16* __restrict__ Bm, const u16* __restrict__ Blo,
    void* __restrict__ Cv, int N, int K,
    int lda, int ldb, int ldc,
    long batchA, long batchB, long batchC, float alpha)
{
  constexpr int TM = WM * MT * 16;
  constexpr int TN = WN * NT * 16;
  constexpr int THREADS = WM * WN * 64;
  constexpr int ASZ = TM * 32, BSZ = TN * 32;

  __shared__ u16 smem[(SPLIT ? 2 : 1) * (ASZ + BSZ)];
  u16* sA  = smem;
  u16* sB  = smem + ASZ;
  u16* sAl = smem + ASZ + BSZ;
  u16* sBl = smem + 2 * ASZ + BSZ;

  const int z = blockIdx.z;
  const u16* Ab = A + (size_t)z * batchA;
  const u16* Bb = Bm + (size_t)z * batchB;
  const int m0 = blockIdx.y * TM;
  const int n0 = blockIdx.x * TN;
  const int tid = threadIdx.x;
  const int lane = tid & 63;
  const int wave = tid >> 6;
  const int wm = wave % WM;
  const int wn = wave / WM;
  const int fr = lane & 15;   // row within 16x16 frag
  const int fg = lane >> 4;   // k-chunk (8 bf16 each)

  f32x4 acc[MT][NT];
  const f32x4 zero = {0.f, 0.f, 0.f, 0.f};
  #pragma unroll
  for (int i = 0; i < MT; i++) {
    #pragma unroll
    for (int j = 0; j < NT; j++) acc[i][j] = zero;
  }

  for (int k0 = 0; k0 < K; k0 += 32) {
    __syncthreads();   // previous tile fully consumed
    for (int s = tid; s < TM * 4; s += THREADS) {
      const int row = s >> 2, ch = s & 3;
      const size_t go = (size_t)(m0 + row) * lda + k0 + ch * 8;
      GLD_LDS16(Ab + go, &sA[s * 8]);
      if constexpr (SPLIT) GLD_LDS16(Alo + (size_t)z * batchA + go, &sAl[s * 8]);
    }
    for (int s = tid; s < TN * 4; s += THREADS) {
      const int row = s >> 2, ch = s & 3;
      int rr = n0 + row; if (rr > N - 1) rr = N - 1;  // clamp (epilogue masks cols >= N)
      const size_t go = (size_t)rr * ldb + k0 + ch * 8;
      GLD_LDS16(Bb + go, &sB[s * 8]);
      if constexpr (SPLIT) GLD_LDS16(Blo + (size_t)z * batchB + go, &sBl[s * 8]);
    }
    __syncthreads();   // drains vmcnt(0) before barrier (m97 semantics)

    bf16x8 av[MT], bv[NT];
    #pragma unroll
    for (int mt = 0; mt < MT; mt++)
      av[mt] = *(const bf16x8*)&sA[((wm * MT + mt) * 16 + fr) * 32 + fg * 8];
    #pragma unroll
    for (int nt = 0; nt < NT; nt++)
      bv[nt] = *(const bf16x8*)&sB[((wn * NT + nt) * 16 + fr) * 32 + fg * 8];
    #pragma unroll
    for (int mt = 0; mt < MT; mt++) {
      #pragma unroll
      for (int nt = 0; nt < NT; nt++)
        acc[mt][nt] = __builtin_amdgcn_mfma_f32_16x16x32_bf16(av[mt], bv[nt], acc[mt][nt], 0, 0, 0);
    }
    if constexpr (SPLIT) {
      bf16x8 al[MT], bl[NT];
      #pragma unroll
      for (int mt = 0; mt < MT; mt++)
        al[mt] = *(const bf16x8*)&sAl[((wm * MT + mt) * 16 + fr) * 32 + fg * 8];
      #pragma unroll
      for (int nt = 0; nt < NT; nt++)
        bl[nt] = *(const bf16x8*)&sBl[((wn * NT + nt) * 16 + fr) * 32 + fg * 8];
      #pragma unroll
      for (int mt = 0; mt < MT; mt++) {
        #pragma unroll
        for (int nt = 0; nt < NT; nt++) {
          acc[mt][nt] = __builtin_amdgcn_mfma_f32_16x16x32_bf16(al[mt], bv[nt], acc[mt][nt], 0, 0, 0);
          acc[mt][nt] = __builtin_amdgcn_mfma_f32_16x16x32_bf16(av[mt], bl[nt], acc[mt][nt], 0, 0, 0);
        }
      }
    }
  }

  // epilogue: C/D layout col = lane&15, row = (lane>>4)*4 + reg (m89-verified)
  const int er = (lane >> 4) * 4;
  const int ec = lane & 15;
  #pragma unroll
  for (int mt = 0; mt < MT; mt++) {
    #pragma unroll
    for (int nt = 0; nt < NT; nt++) {
      const int row = m0 + (wm * MT + mt) * 16 + er;
      const int col = n0 + (wn * NT + nt) * 16 + ec;
      if (col < N) {
        #pragma unroll
        for (int r2 = 0; r2 < 4; r2++) {
          const float vv = acc[mt][nt][r2] * alpha;
          const size_t ci = (size_t)z * batchC + (size_t)(row + r2) * ldc + col;
          if constexpr (CBF16) ((u16*)Cv)[ci] = f2bf(vv);
          else                 ((float*)Cv)[ci] = vv;
        }
      }
    }
  }
}

// ---------------------------------------------------------------------------
// Reductions (256-thread blocks, 4 waves)
// ---------------------------------------------------------------------------
__device__ __forceinline__ float block_max256(float v, float* red) {
  #pragma unroll
  for (int m = 32; m > 0; m >>= 1) v = fmaxf(v, __shfl_xor(v, m, 64));
  if ((threadIdx.x & 63) == 0) red[threadIdx.x >> 6] = v;
  __syncthreads();
  const float r = fmaxf(fmaxf(red[0], red[1]), fmaxf(red[2], red[3]));
  __syncthreads();
  return r;
}
__device__ __forceinline__ float block_sum256(float v, float* red) {
  #pragma unroll
  for (int m = 32; m > 0; m >>= 1) v += __shfl_xor(v, m, 64);
  if ((threadIdx.x & 63) == 0) red[threadIdx.x >> 6] = v;
  __syncthreads();
  const float r = (red[0] + red[1]) + (red[2] + red[3]);
  __syncthreads();
  return r;
}

// ---------------------------------------------------------------------------
// Casts
// ---------------------------------------------------------------------------
__global__ __launch_bounds__(256) void cast_bf16(const float* __restrict__ in, u16* __restrict__ out) {
  const size_t i = ((size_t)blockIdx.x * 256 + threadIdx.x) * 4;
  const float4 v = *(const float4*)(in + i);
  ushort4 o;
  o.x = f2bf(v.x); o.y = f2bf(v.y); o.z = f2bf(v.z); o.w = f2bf(v.w);
  *(ushort4*)(out + i) = o;
}
__global__ __launch_bounds__(256) void cast_split(const float* __restrict__ in,
                                                  u16* __restrict__ hi, u16* __restrict__ lo) {
  const size_t i = ((size_t)blockIdx.x * 256 + threadIdx.x) * 4;
  const float4 v = *(const float4*)(in + i);
  ushort4 oh, ol;
  oh.x = f2bf(v.x); ol.x = f2bf(v.x - bf2f(oh.x));
  oh.y = f2bf(v.y); ol.y = f2bf(v.y - bf2f(oh.y));
  oh.z = f2bf(v.z); ol.z = f2bf(v.z - bf2f(oh.z));
  oh.w = f2bf(v.w); ol.w = f2bf(v.w - bf2f(oh.w));
  *(ushort4*)(hi + i) = oh;
  *(ushort4*)(lo + i) = ol;
}

// ---------------------------------------------------------------------------
// sc[b,t] = ||echo[b,t,:]||^2 / 32   (echo_back GEMM eliminated algebraically)
// ---------------------------------------------------------------------------
__global__ __launch_bounds__(256) void sc_kernel(const float* __restrict__ echo, float* __restrict__ sc) {
  const int row = blockIdx.x;
  const float4 v = ((const float4*)(echo + (size_t)row * E_))[threadIdx.x];
  float ss = v.x * v.x + v.y * v.y + v.z * v.z + v.w * v.w;
  __shared__ float red[4];
  ss = block_sum256(ss, red);
  if (threadIdx.x == 0) sc[row] = ss * (1.0f / 32.0f);
}

// ---------------------------------------------------------------------------
// s2[b,h,t] = dot(x[b,t,:], wr[h,:,t]) / 8
// ---------------------------------------------------------------------------
__global__ __launch_bounds__(256) void s2_kernel(
    const float* __restrict__ x, const float* __restrict__ wr, float* __restrict__ s2) {
  const int t = blockIdx.x * 256 + threadIdx.x;
  const int h = blockIdx.y, b = blockIdx.z;
  const float* xr = x + ((size_t)b * T_ + t) * E_;
  const float* wc = wr + (size_t)h * E_ * T_ + t;
  float acc = 0.f;
  #pragma unroll 8
  for (int e = 0; e < E_; e++) acc += xr[e] * wc[(size_t)e * T_];
  s2[((size_t)b * H_ + h) * T_ + t] = acc * 0.125f;
}

// ---------------------------------------------------------------------------
// In-place causal softmax over bf16 score rows (per b slab: layout h,i,j)
// ---------------------------------------------------------------------------
__global__ __launch_bounds__(256) void softmax_causal(u16* __restrict__ S) {
  const int i = blockIdx.x;
  const int h = blockIdx.y;
  u16* row = S + ((size_t)h * T_ + i) * T_;
  __shared__ float red[4];
  float v[4];
  float m = -3.0e38f;
  #pragma unroll
  for (int k = 0; k < 4; k++) {
    const int j = threadIdx.x + k * 256;
    const float xv = (j <= i) ? bf2f(row[j]) : -3.0e38f;
    v[k] = xv;
    m = fmaxf(m, xv);
  }
  m = block_max256(m, red);
  float s = 0.f;
  #pragma unroll
  for (int k = 0; k < 4; k++) {
    const int j = threadIdx.x + k * 256;
    const float p = (j <= i) ? __expf(v[k] - m) : 0.f;
    v[k] = p;
    s += p;
  }
  s = block_sum256(s, red);
  const float inv = 1.0f / s;
  #pragma unroll
  for (int k = 0; k < 4; k++) {
    const int j = threadIdx.x + k * 256;
    row[j] = f2bf(v[k] * inv);
  }
}

// ---------------------------------------------------------------------------
// a3[b,i,j] = softmax_{j<=i}(sc_i*sc_j), written bf16 (zeros above diagonal)
// ---------------------------------------------------------------------------
__global__ __launch_bounds__(256) void a3_softmax(const float* __restrict__ sc, u16* __restrict__ a3) {
  const int i = blockIdx.x;
  const int b = blockIdx.y;
  const float* sr = sc + (size_t)b * T_;
  const float sci = sr[i];
  u16* row = a3 + ((size_t)b * T_ + i) * T_;
  __shared__ float red[4];
  float v[4];
  float m = -3.0e38f;
  #pragma unroll
  for (int k = 0; k < 4; k++) {
    const int j = threadIdx.x + k * 256;
    const float xv = (j <= i) ? sci * sr[j] : -3.0e38f;
    v[k] = xv;
    m = fmaxf(m, xv);
  }
  m = block_max256(m, red);
  float s = 0.f;
  #pragma unroll
  for (int k = 0; k < 4; k++) {
    const int j = threadIdx.x + k * 256;
    const float p = (j <= i) ? __expf(v[k] - m) : 0.f;
    v[k] = p;
    s += p;
  }
  s = block_sum256(s, red);
  const float inv = 1.0f / s;
  #pragma unroll
  for (int k = 0; k < 4; k++) {
    const int j = threadIdx.x + k * 256;
    row[j] = f2bf(v[k] * inv);
  }
}

// ---------------------------------------------------------------------------
// Branch 2: broadcast-key softmax => prefix scan, parallelized.
// One 1024-thread block per (b,h): lane = d (64), wave = j-chunk (16 x 64).
// Phase 1: block max. Phase 2: exp weights to LDS (removes exp from the
// serial chain). Phase 3: per-chunk totals. Phase 4: exclusive chunk offsets.
// Phase 5: 64-step inclusive re-walk writing num/den. Serial chain 1024 -> 128.
// ---------------------------------------------------------------------------
__global__ __launch_bounds__(1024) void branch2_scan(
    const float* __restrict__ s2, const u16* __restrict__ rv, u16* __restrict__ out2) {
  const int h = blockIdx.x, b = blockIdx.y;
  const int tid = threadIdx.x;
  const int lane = tid & 63;   // d
  const int wv = tid >> 6;     // j-chunk index, 0..15

  const float* srow = s2 + ((size_t)b * H_ + h) * T_;

  __shared__ float wbuf[T_];          // exp weights
  __shared__ float numtot[16][64];    // per-chunk sum of w*rv[d]
  __shared__ float dentot[16];        // per-chunk sum of w
  __shared__ float redm[16];

  // 1. block max over the full row (one element per thread)
  float m = srow[tid];
  #pragma unroll
  for (int mk = 32; mk > 0; mk >>= 1) m = fmaxf(m, __shfl_xor(m, mk, 64));
  if (lane == 0) redm[wv] = m;
  __syncthreads();
  m = redm[0];
  #pragma unroll
  for (int i2 = 1; i2 < 16; i2++) m = fmaxf(m, redm[i2]);

  // 2. all weights in one parallel shot
  wbuf[tid] = __expf(srow[tid] - m);
  __syncthreads();

  // 3. chunk totals (64-step fma chain; rv loads coalesced 128B/wave)
  const u16* rvp = rv + (size_t)b * T_ * E_ + h * D_ + lane;
  const int j0 = wv * 64;
  float num = 0.f, den = 0.f;
  #pragma unroll 8
  for (int j2 = 0; j2 < 64; j2++) {
    const float w = wbuf[j0 + j2];
    den += w;
    num += w * bf2f(rvp[(size_t)(j0 + j2) * E_]);
  }
  numtot[wv][lane] = num;
  if (lane == 0) dentot[wv] = den;
  __syncthreads();

  // 4. exclusive offsets (wave-uniform trip count — no divergence cost)
  float num_off = 0.f, den_off = 0.f;
  for (int w2 = 0; w2 < wv; w2++) {
    num_off += numtot[w2][lane];
    den_off += dentot[w2];
  }

  // 5. inclusive re-walk, write out
  u16* op = out2 + (size_t)b * T_ * E_ + h * D_ + lane;
  num = num_off; den = den_off;
  #pragma unroll 8
  for (int j2 = 0; j2 < 64; j2++) {
    const float w = wbuf[j0 + j2];
    num += w * bf2f(rvp[(size_t)(j0 + j2) * E_]);
    den += w;
    op[(size_t)(j0 + j2) * E_] = f2bf(num / den);
  }
}

// ---------------------------------------------------------------------------
// Transposes
// ---------------------------------------------------------------------------
__global__ __launch_bounds__(256) void transpose_v(const u16* __restrict__ v, u16* __restrict__ vT) {
  // v: (B,T,H*D) -> vT: (B,H,D,T); grid (B*H, D/32, T/32)
  const int bh = blockIdx.x;
  const int b = bh >> 4, h = bh & 15;
  const int d0 = blockIdx.y * 32, t0 = blockIdx.z * 32;
  __shared__ u16 tile[32][33];
  const int c = threadIdx.x & 31, r0 = threadIdx.x >> 5;
  #pragma unroll
  for (int rr = 0; rr < 32; rr += 8) {
    const int t = t0 + r0 + rr;
    tile[r0 + rr][c] = v[((size_t)b * T_ + t) * E_ + h * 64 + d0 + c];
  }
  __syncthreads();
  #pragma unroll
  for (int rr = 0; rr < 32; rr += 8) {
    const int d = d0 + r0 + rr;
    vT[((size_t)bh * D_ + d) * T_ + t0 + c] = tile[c][r0 + rr];
  }
}

__global__ __launch_bounds__(256) void transpose_echo(const float* __restrict__ e, u16* __restrict__ eT) {
  // e: (B,T,E) f32 -> eT: (B,E,T) bf16; grid (B, E/32, T/32)
  const int b = blockIdx.x;
  const int f0 = blockIdx.y * 32, t0 = blockIdx.z * 32;
  __shared__ float tile[32][33];
  const int c = threadIdx.x & 31, r0 = threadIdx.x >> 5;
  #pragma unroll
  for (int rr = 0; rr < 32; rr += 8) {
    const int t = t0 + r0 + rr;
    tile[r0 + rr][c] = e[((size_t)b * T_ + t) * E_ + f0 + c];
  }
  __syncthreads();
  #pragma unroll
  for (int rr = 0; rr < 32; rr += 8) {
    const int f = f0 + r0 + rr;
    eT[((size_t)b * E_ + f) * T_ + t0 + c] = f2bf(tile[c][r0 + rr]);
  }
}

// ---------------------------------------------------------------------------
// Gated combine: comb = g0*out1 + g1*out2 + g2*out3, g = softmax(gate[h,:])
// ---------------------------------------------------------------------------
__global__ __launch_bounds__(256) void combine_gate(
    const u16* __restrict__ o1, const u16* __restrict__ o2, const u16* __restrict__ o3,
    const float* __restrict__ gate, u16* __restrict__ comb) {
  const size_t idx = (size_t)blockIdx.x * 256 + threadIdx.x;
  const int f = (int)(idx & (E_ - 1));
  const int h = f >> 6;
  const float g0 = gate[h * 3 + 0], g1 = gate[h * 3 + 1], g2 = gate[h * 3 + 2];
  const float mx = fmaxf(g0, fmaxf(g1, g2));
  const float e0 = __expf(g0 - mx), e1 = __expf(g1 - mx), e2 = __expf(g2 - mx);
  const float inv = 1.0f / (e0 + e1 + e2);
  const float o = (e0 * bf2f(o1[idx]) + e1 * bf2f(o2[idx]) + e2 * bf2f(o3[idx])) * inv;
  comb[idx] = f2bf(o);
}

// ---------------------------------------------------------------------------
extern "C" void kernel_launch(void* const* d_in, const int* in_sizes, int n_in,
                              void* d_out, int out_size, void* d_ws, size_t ws_size,
                              hipStream_t stream) {
  (void)in_sizes; (void)n_in; (void)out_size; (void)ws_size;
  const float* x    = (const float*)d_in[0];
  const float* wq   = (const float*)d_in[1];
  const float* wk   = (const float*)d_in[2];
  const float* wv   = (const float*)d_in[3];
  const float* wvr  = (const float*)d_in[4];
  const float* wr   = (const float*)d_in[5];
  const float* wj   = (const float*)d_in[6];
  const float* gate = (const float*)d_in[7];
  const float* wo   = (const float*)d_in[8];
  float* out = (float*)d_out;

  char* p = (char*)d_ws;
  auto alloc = [&](size_t bytes) -> char* {
    char* r = p; p += (bytes + 255) & ~(size_t)255; return r;
  };
  const size_t NTE = (size_t)B_ * T_ * E_;   // 4M elements
  const size_t NW  = (size_t)E_ * E_;        // 1M elements

  u16* xb    = (u16*)alloc(NTE * 2);
  u16* xlo   = (u16*)alloc(NTE * 2);
  u16* wqb   = (u16*)alloc(NW * 2);
  u16* wkb   = (u16*)alloc(NW * 2);
  u16* wvb   = (u16*)alloc(NW * 2);
  u16* wvrb  = (u16*)alloc(NW * 2);
  u16* wjb   = (u16*)alloc(NW * 2);
  u16* wjlo  = (u16*)alloc(NW * 2);
  u16* wob   = (u16*)alloc(NW * 2);
  u16* qb    = (u16*)alloc(NTE * 2);
  u16* kb    = (u16*)alloc(NTE * 2);
  u16* vb    = (u16*)alloc(NTE * 2);
  u16* rvb   = (u16*)alloc(NTE * 2);
  u16* vT    = (u16*)alloc(NTE * 2);
  float* echoF = (float*)alloc(NTE * 4);
  u16* echoT = (u16*)alloc(NTE * 2);
  u16* a3p   = (u16*)alloc(NTE * 2);
  float* sc  = (float*)alloc((size_t)B_ * T_ * 4);
  float* s2  = (float*)alloc((size_t)B_ * H_ * T_ * 4);
  u16* out1b = (u16*)alloc(NTE * 2);
  u16* out2b = (u16*)alloc(NTE * 2);
  u16* out3b = (u16*)alloc(NTE * 2);
  u16* comb  = (u16*)alloc(NTE * 2);
  u16* s1buf = (u16*)alloc((size_t)H_ * T_ * T_ * 2);  // per-b slab, 32 MB

  // ---- casts ----
  cast_split<<<dim3((unsigned)(NTE / 1024)), 256, 0, stream>>>(x, xb, xlo);
  cast_bf16 <<<dim3((unsigned)(NW / 1024)), 256, 0, stream>>>(wq, wqb);
  cast_bf16 <<<dim3((unsigned)(NW / 1024)), 256, 0, stream>>>(wk, wkb);
  cast_bf16 <<<dim3((unsigned)(NW / 1024)), 256, 0, stream>>>(wv, wvb);
  cast_bf16 <<<dim3((unsigned)(NW / 1024)), 256, 0, stream>>>(wvr, wvrb);
  cast_bf16 <<<dim3((unsigned)(NW / 1024)), 256, 0, stream>>>(wo, wob);
  cast_split<<<dim3((unsigned)(NW / 1024)), 256, 0, stream>>>(wj, wjb, wjlo);

  // ---- projections: (B*T,E) @ W^T ----
  const dim3 gproj(E_ / 128, (B_ * T_) / 128, 1);
  gemm_bt<2,2,4,4,false,true><<<gproj, 256, 0, stream>>>(
      xb, nullptr, wqb, nullptr, qb, E_, E_, E_, E_, E_, 0L, 0L, 0L, 1.f);
  gemm_bt<2,2,4,4,false,true><<<gproj, 256, 0, stream>>>(
      xb, nullptr, wkb, nullptr, kb, E_, E_, E_, E_, E_, 0L, 0L, 0L, 1.f);
  gemm_bt<2,2,4,4,false,true><<<gproj, 256, 0, stream>>>(
      xb, nullptr, wvb, nullptr, vb, E_, E_, E_, E_, E_, 0L, 0L, 0L, 1.f);
  gemm_bt<2,2,4,4,false,true><<<gproj, 256, 0, stream>>>(
      xb, nullptr, wvrb, nullptr, rvb, E_, E_, E_, E_, E_, 0L, 0L, 0L, 1.f);
  // echo in split-bf16 (fp32-class accuracy; feeds sc = ||echo||^2/32)
  gemm_bt<2,2,4,4,true,false><<<gproj, 256, 0, stream>>>(
      xb, xlo, wjb, wjlo, echoF, E_, E_, E_, E_, E_, 0L, 0L, 0L, 1.f);

  // ---- small/side computations ----
  transpose_v<<<dim3(B_ * H_, D_ / 32, T_ / 32), 256, 0, stream>>>(vb, vT);
  sc_kernel<<<dim3(B_ * T_), 256, 0, stream>>>(echoF, sc);
  transpose_echo<<<dim3(B_, E_ / 32, T_ / 32), 256, 0, stream>>>(echoF, echoT);
  s2_kernel<<<dim3(T_ / 256, H_, B_), 256, 0, stream>>>(x, wr, s2);

  // ---- branch 2: parallel hierarchical prefix scan ----
  branch2_scan<<<dim3(H_, B_), 1024, 0, stream>>>(s2, rvb, out2b);

  // ---- branch 3: a3 softmax + batched GEMM out3 = a3 @ echo ----
  a3_softmax<<<dim3(T_, B_), 256, 0, stream>>>(sc, a3p);
  gemm_bt<2,2,4,4,false,true><<<dim3(E_ / 128, T_ / 128, B_), 256, 0, stream>>>(
      a3p, nullptr, echoT, nullptr, out3b, E_, T_, T_, T_, E_,
      (long)T_ * T_, (long)E_ * T_, (long)T_ * E_, 1.f);

  // ---- branch 1: per-b materialized scores (s1buf reused across b) ----
  for (int b = 0; b < B_; b++) {
    const size_t bTE = (size_t)b * T_ * E_;
    // s1[h,i,j] = q . k / 8   (batch over h via z; A,B col-offset h*64)
    gemm_bt<2,2,4,4,false,true><<<dim3(T_ / 128, T_ / 128, H_), 256, 0, stream>>>(
        qb + bTE, nullptr, kb + bTE, nullptr, s1buf, T_, D_, E_, E_, T_,
        64L, 64L, (long)T_ * T_, 0.125f);
    softmax_causal<<<dim3(T_, H_), 256, 0, stream>>>(s1buf);
    // out1[b,i,h*64+d] = a1 @ v   (N=64 narrow config)
    gemm_bt<4,1,2,4,false,true><<<dim3(1, T_ / 128, H_), 256, 0, stream>>>(
        s1buf, nullptr, vT + (size_t)b * H_ * D_ * T_, nullptr, out1b + bTE,
        D_, T_, T_, T_, E_, (long)T_ * T_, (long)D_ * T_, 64L, 1.f);
  }

  // ---- combine + output projection ----
  combine_gate<<<dim3((unsigned)(NTE / 256)), 256, 0, stream>>>(out1b, out2b, out3b, gate, comb);
  gemm_bt<2,2,4,4,false,false><<<gproj, 256, 0, stream>>>(
      comb, nullptr, wob, nullptr, out, E_, E_, E_, E_, E_, 0L, 0L, 0L, 1.f);
}

// Round 3
// 679.469 us; speedup vs baseline: 1.2031x; 1.0728x over previous
//
#include <hip/hip_runtime.h>
#include <cstdint>
#include <cstddef>

typedef unsigned short u16;
typedef short bf16x8 __attribute__((ext_vector_type(8)));
typedef float f32x4 __attribute__((ext_vector_type(4)));

constexpr int B_ = 4, T_ = 1024, E_ = 1024, H_ = 16, D_ = 64;

__device__ __forceinline__ float bf2f(u16 u) {
  union { unsigned u; float f; } v; v.u = ((unsigned)u) << 16; return v.f;
}
__device__ __forceinline__ u16 f2bf(float f) {
  union { float f; unsigned u; } v; v.f = f;
  return (u16)((v.u + 0x7fffu + ((v.u >> 16) & 1u)) >> 16);
}

#define GLD_LDS16(gp, lp)                                                      \
  __builtin_amdgcn_global_load_lds(                                            \
      (const __attribute__((address_space(1))) void*)(gp),                     \
      (__attribute__((address_space(3))) void*)(lp), 16, 0, 0)

// ---------------------------------------------------------------------------
// Tiled bf16 MFMA GEMM, C = alpha * A @ B^T.  (m97 structure; see round 0)
// ---------------------------------------------------------------------------
template<int WM, int WN, int MT, int NT, bool SPLIT, bool CBF16>
__global__ __launch_bounds__(WM * WN * 64) void gemm_bt(
    const u16* __restrict__ A, const u16* __restrict__ Alo,
    const u16* __restrict__ Bm, const u16* __restrict__ Blo,
    void* __restrict__ Cv, int N, int K,
    int lda, int ldb, int ldc,
    long batchA, long batchB, long batchC, float alpha)
{
  constexpr int TM = WM * MT * 16;
  constexpr int TN = WN * NT * 16;
  constexpr int THREADS = WM * WN * 64;
  constexpr int ASZ = TM * 32, BSZ = TN * 32;

  __shared__ u16 smem[(SPLIT ? 2 : 1) * (ASZ + BSZ)];
  u16* sA  = smem;
  u16* sB  = smem + ASZ;
  u16* sAl = smem + ASZ + BSZ;
  u16* sBl = smem + 2 * ASZ + BSZ;

  const int z = blockIdx.z;
  const u16* Ab = A + (size_t)z * batchA;
  const u16* Bb = Bm + (size_t)z * batchB;
  const int m0 = blockIdx.y * TM;
  const int n0 = blockIdx.x * TN;
  const int tid = threadIdx.x;
  const int lane = tid & 63;
  const int wave = tid >> 6;
  const int wm = wave % WM;
  const int wn = wave / WM;
  const int fr = lane & 15;   // row within 16x16 frag
  const int fg = lane >> 4;   // k-chunk (8 bf16 each)

  f32x4 acc[MT][NT];
  const f32x4 zero = {0.f, 0.f, 0.f, 0.f};
  #pragma unroll
  for (int i = 0; i < MT; i++) {
    #pragma unroll
    for (int j = 0; j < NT; j++) acc[i][j] = zero;
  }

  for (int k0 = 0; k0 < K; k0 += 32) {
    __syncthreads();   // previous tile fully consumed
    for (int s = tid; s < TM * 4; s += THREADS) {
      const int row = s >> 2, ch = s & 3;
      const size_t go = (size_t)(m0 + row) * lda + k0 + ch * 8;
      GLD_LDS16(Ab + go, &sA[s * 8]);
      if constexpr (SPLIT) GLD_LDS16(Alo + (size_t)z * batchA + go, &sAl[s * 8]);
    }
    for (int s = tid; s < TN * 4; s += THREADS) {
      const int row = s >> 2, ch = s & 3;
      int rr = n0 + row; if (rr > N - 1) rr = N - 1;  // clamp (epilogue masks cols >= N)
      const size_t go = (size_t)rr * ldb + k0 + ch * 8;
      GLD_LDS16(Bb + go, &sB[s * 8]);
      if constexpr (SPLIT) GLD_LDS16(Blo + (size_t)z * batchB + go, &sBl[s * 8]);
    }
    __syncthreads();   // drains vmcnt(0) before barrier (m97 semantics)

    bf16x8 av[MT], bv[NT];
    #pragma unroll
    for (int mt = 0; mt < MT; mt++)
      av[mt] = *(const bf16x8*)&sA[((wm * MT + mt) * 16 + fr) * 32 + fg * 8];
    #pragma unroll
    for (int nt = 0; nt < NT; nt++)
      bv[nt] = *(const bf16x8*)&sB[((wn * NT + nt) * 16 + fr) * 32 + fg * 8];
    #pragma unroll
    for (int mt = 0; mt < MT; mt++) {
      #pragma unroll
      for (int nt = 0; nt < NT; nt++)
        acc[mt][nt] = __builtin_amdgcn_mfma_f32_16x16x32_bf16(av[mt], bv[nt], acc[mt][nt], 0, 0, 0);
    }
    if constexpr (SPLIT) {
      bf16x8 al[MT], bl[NT];
      #pragma unroll
      for (int mt = 0; mt < MT; mt++)
        al[mt] = *(const bf16x8*)&sAl[((wm * MT + mt) * 16 + fr) * 32 + fg * 8];
      #pragma unroll
      for (int nt = 0; nt < NT; nt++)
        bl[nt] = *(const bf16x8*)&sBl[((wn * NT + nt) * 16 + fr) * 32 + fg * 8];
      #pragma unroll
      for (int mt = 0; mt < MT; mt++) {
        #pragma unroll
        for (int nt = 0; nt < NT; nt++) {
          acc[mt][nt] = __builtin_amdgcn_mfma_f32_16x16x32_bf16(al[mt], bv[nt], acc[mt][nt], 0, 0, 0);
          acc[mt][nt] = __builtin_amdgcn_mfma_f32_16x16x32_bf16(av[mt], bl[nt], acc[mt][nt], 0, 0, 0);
        }
      }
    }
  }

  // epilogue: C/D layout col = lane&15, row = (lane>>4)*4 + reg (m89-verified)
  const int er = (lane >> 4) * 4;
  const int ec = lane & 15;
  #pragma unroll
  for (int mt = 0; mt < MT; mt++) {
    #pragma unroll
    for (int nt = 0; nt < NT; nt++) {
      const int row = m0 + (wm * MT + mt) * 16 + er;
      const int col = n0 + (wn * NT + nt) * 16 + ec;
      if (col < N) {
        #pragma unroll
        for (int r2 = 0; r2 < 4; r2++) {
          const float vv = acc[mt][nt][r2] * alpha;
          const size_t ci = (size_t)z * batchC + (size_t)(row + r2) * ldc + col;
          if constexpr (CBF16) ((u16*)Cv)[ci] = f2bf(vv);
          else                 ((float*)Cv)[ci] = vv;
        }
      }
    }
  }
}

// ---------------------------------------------------------------------------
// Reductions (256-thread blocks, 4 waves)
// ---------------------------------------------------------------------------
__device__ __forceinline__ float block_max256(float v, float* red) {
  #pragma unroll
  for (int m = 32; m > 0; m >>= 1) v = fmaxf(v, __shfl_xor(v, m, 64));
  if ((threadIdx.x & 63) == 0) red[threadIdx.x >> 6] = v;
  __syncthreads();
  const float r = fmaxf(fmaxf(red[0], red[1]), fmaxf(red[2], red[3]));
  __syncthreads();
  return r;
}
__device__ __forceinline__ float block_sum256(float v, float* red) {
  #pragma unroll
  for (int m = 32; m > 0; m >>= 1) v += __shfl_xor(v, m, 64);
  if ((threadIdx.x & 63) == 0) red[threadIdx.x >> 6] = v;
  __syncthreads();
  const float r = (red[0] + red[1]) + (red[2] + red[3]);
  __syncthreads();
  return r;
}

// ---------------------------------------------------------------------------
// Casts
// ---------------------------------------------------------------------------
__global__ __launch_bounds__(256) void cast_bf16(const float* __restrict__ in, u16* __restrict__ out) {
  const size_t i = ((size_t)blockIdx.x * 256 + threadIdx.x) * 4;
  const float4 v = *(const float4*)(in + i);
  ushort4 o;
  o.x = f2bf(v.x); o.y = f2bf(v.y); o.z = f2bf(v.z); o.w = f2bf(v.w);
  *(ushort4*)(out + i) = o;
}
__global__ __launch_bounds__(256) void cast_split(const float* __restrict__ in,
                                                  u16* __restrict__ hi, u16* __restrict__ lo) {
  const size_t i = ((size_t)blockIdx.x * 256 + threadIdx.x) * 4;
  const float4 v = *(const float4*)(in + i);
  ushort4 oh, ol;
  oh.x = f2bf(v.x); ol.x = f2bf(v.x - bf2f(oh.x));
  oh.y = f2bf(v.y); ol.y = f2bf(v.y - bf2f(oh.y));
  oh.z = f2bf(v.z); ol.z = f2bf(v.z - bf2f(oh.z));
  oh.w = f2bf(v.w); ol.w = f2bf(v.w - bf2f(oh.w));
  *(ushort4*)(hi + i) = oh;
  *(ushort4*)(lo + i) = ol;
}

// ---------------------------------------------------------------------------
// sc[b,t] = ||echo[b,t,:]||^2 / 32   (echo_back GEMM eliminated algebraically)
// ---------------------------------------------------------------------------
__global__ __launch_bounds__(256) void sc_kernel(const float* __restrict__ echo, float* __restrict__ sc) {
  const int row = blockIdx.x;
  const float4 v = ((const float4*)(echo + (size_t)row * E_))[threadIdx.x];
  float ss = v.x * v.x + v.y * v.y + v.z * v.z + v.w * v.w;
  __shared__ float red[4];
  ss = block_sum256(ss, red);
  if (threadIdx.x == 0) sc[row] = ss * (1.0f / 32.0f);
}

// ---------------------------------------------------------------------------
// transpose_wr: wr (H,E,T) f32 -> wrT (H,T,E) bf16; grid (H, T/32, E/32)
// ---------------------------------------------------------------------------
__global__ __launch_bounds__(256) void transpose_wr(const float* __restrict__ wr, u16* __restrict__ wrT) {
  const int h = blockIdx.x;
  const int t0 = blockIdx.y * 32, e0 = blockIdx.z * 32;
  __shared__ float tile[32][33];
  const int c = threadIdx.x & 31, r0 = threadIdx.x >> 5;
  #pragma unroll
  for (int rr = 0; rr < 32; rr += 8) {
    const int e = e0 + r0 + rr;
    tile[r0 + rr][c] = wr[((size_t)h * E_ + e) * T_ + t0 + c];   // coalesced in t
  }
  __syncthreads();
  #pragma unroll
  for (int rr = 0; rr < 32; rr += 8) {
    const int t = t0 + r0 + rr;
    wrT[((size_t)h * T_ + t) * E_ + e0 + c] = f2bf(tile[c][r0 + rr]);  // coalesced in e
  }
}

// ---------------------------------------------------------------------------
// s2_fast: s2[b,h,t] = dot(xb[b,t,:], wrT[h,t,:]) / 8.
// One block per (b,t); wave w handles heads {w, w+4, w+8, w+12}.
// All loads coalesced 16B/lane bf16x8; wave shuffle-reduce.
// ---------------------------------------------------------------------------
__global__ __launch_bounds__(256) void s2_fast(
    const u16* __restrict__ xb, const u16* __restrict__ wrT, float* __restrict__ s2) {
  const int t = blockIdx.x, b = blockIdx.y;
  const int lane = threadIdx.x & 63;
  const int wv = threadIdx.x >> 6;
  const u16* xr = xb + ((size_t)b * T_ + t) * E_ + lane * 16;
  const bf16x8 xv0 = *(const bf16x8*)xr;
  const bf16x8 xv1 = *(const bf16x8*)(xr + 8);
  #pragma unroll
  for (int hh = 0; hh < 4; hh++) {
    const int h = wv + hh * 4;
    const u16* wp = wrT + ((size_t)h * T_ + t) * E_ + lane * 16;
    const bf16x8 w0 = *(const bf16x8*)wp;
    const bf16x8 w1 = *(const bf16x8*)(wp + 8);
    float acc = 0.f;
    #pragma unroll
    for (int i2 = 0; i2 < 8; i2++) {
      acc += bf2f((u16)xv0[i2]) * bf2f((u16)w0[i2]);
      acc += bf2f((u16)xv1[i2]) * bf2f((u16)w1[i2]);
    }
    #pragma unroll
    for (int mk = 32; mk > 0; mk >>= 1) acc += __shfl_xor(acc, mk, 64);
    if (lane == 0) s2[((size_t)b * H_ + h) * T_ + t] = acc * 0.125f;
  }
}

// ---------------------------------------------------------------------------
// In-place causal softmax over bf16 score rows (per b slab: layout h,i,j)
// ---------------------------------------------------------------------------
__global__ __launch_bounds__(256) void softmax_causal(u16* __restrict__ S) {
  const int i = blockIdx.x;
  const int h = blockIdx.y;
  u16* row = S + ((size_t)h * T_ + i) * T_;
  __shared__ float red[4];
  float v[4];
  float m = -3.0e38f;
  #pragma unroll
  for (int k = 0; k < 4; k++) {
    const int j = threadIdx.x + k * 256;
    const float xv = (j <= i) ? bf2f(row[j]) : -3.0e38f;
    v[k] = xv;
    m = fmaxf(m, xv);
  }
  m = block_max256(m, red);
  float s = 0.f;
  #pragma unroll
  for (int k = 0; k < 4; k++) {
    const int j = threadIdx.x + k * 256;
    const float p = (j <= i) ? __expf(v[k] - m) : 0.f;
    v[k] = p;
    s += p;
  }
  s = block_sum256(s, red);
  const float inv = 1.0f / s;
  #pragma unroll
  for (int k = 0; k < 4; k++) {
    const int j = threadIdx.x + k * 256;
    row[j] = f2bf(v[k] * inv);
  }
}

// ---------------------------------------------------------------------------
// a3[b,i,j] = softmax_{j<=i}(sc_i*sc_j), written bf16 (zeros above diagonal)
// ---------------------------------------------------------------------------
__global__ __launch_bounds__(256) void a3_softmax(const float* __restrict__ sc, u16* __restrict__ a3) {
  const int i = blockIdx.x;
  const int b = blockIdx.y;
  const float* sr = sc + (size_t)b * T_;
  const float sci = sr[i];
  u16* row = a3 + ((size_t)b * T_ + i) * T_;
  __shared__ float red[4];
  float v[4];
  float m = -3.0e38f;
  #pragma unroll
  for (int k = 0; k < 4; k++) {
    const int j = threadIdx.x + k * 256;
    const float xv = (j <= i) ? sci * sr[j] : -3.0e38f;
    v[k] = xv;
    m = fmaxf(m, xv);
  }
  m = block_max256(m, red);
  float s = 0.f;
  #pragma unroll
  for (int k = 0; k < 4; k++) {
    const int j = threadIdx.x + k * 256;
    const float p = (j <= i) ? __expf(v[k] - m) : 0.f;
    v[k] = p;
    s += p;
  }
  s = block_sum256(s, red);
  const float inv = 1.0f / s;
  #pragma unroll
  for (int k = 0; k < 4; k++) {
    const int j = threadIdx.x + k * 256;
    row[j] = f2bf(v[k] * inv);
  }
}

// ---------------------------------------------------------------------------
// Branch 2: broadcast-key softmax => prefix scan, parallelized (round-1 win).
// ---------------------------------------------------------------------------
__global__ __launch_bounds__(1024) void branch2_scan(
    const float* __restrict__ s2, const u16* __restrict__ rv, u16* __restrict__ out2) {
  const int h = blockIdx.x, b = blockIdx.y;
  const int tid = threadIdx.x;
  const int lane = tid & 63;   // d
  const int wv = tid >> 6;     // j-chunk index, 0..15

  const float* srow = s2 + ((size_t)b * H_ + h) * T_;

  __shared__ float wbuf[T_];          // exp weights
  __shared__ float numtot[16][64];    // per-chunk sum of w*rv[d]
  __shared__ float dentot[16];        // per-chunk sum of w
  __shared__ float redm[16];

  // 1. block max over the full row (one element per thread)
  float m = srow[tid];
  #pragma unroll
  for (int mk = 32; mk > 0; mk >>= 1) m = fmaxf(m, __shfl_xor(m, mk, 64));
  if (lane == 0) redm[wv] = m;
  __syncthreads();
  m = redm[0];
  #pragma unroll
  for (int i2 = 1; i2 < 16; i2++) m = fmaxf(m, redm[i2]);

  // 2. all weights in one parallel shot
  wbuf[tid] = __expf(srow[tid] - m);
  __syncthreads();

  // 3. chunk totals (64-step fma chain; rv loads coalesced 128B/wave)
  const u16* rvp = rv + (size_t)b * T_ * E_ + h * D_ + lane;
  const int j0 = wv * 64;
  float num = 0.f, den = 0.f;
  #pragma unroll 8
  for (int j2 = 0; j2 < 64; j2++) {
    const float w = wbuf[j0 + j2];
    den += w;
    num += w * bf2f(rvp[(size_t)(j0 + j2) * E_]);
  }
  numtot[wv][lane] = num;
  if (lane == 0) dentot[wv] = den;
  __syncthreads();

  // 4. exclusive offsets (wave-uniform trip count — no divergence cost)
  float num_off = 0.f, den_off = 0.f;
  for (int w2 = 0; w2 < wv; w2++) {
    num_off += numtot[w2][lane];
    den_off += dentot[w2];
  }

  // 5. inclusive re-walk, write out
  u16* op = out2 + (size_t)b * T_ * E_ + h * D_ + lane;
  num = num_off; den = den_off;
  #pragma unroll 8
  for (int j2 = 0; j2 < 64; j2++) {
    const float w = wbuf[j0 + j2];
    num += w * bf2f(rvp[(size_t)(j0 + j2) * E_]);
    den += w;
    op[(size_t)(j0 + j2) * E_] = f2bf(num / den);
  }
}

// ---------------------------------------------------------------------------
// Transposes
// ---------------------------------------------------------------------------
__global__ __launch_bounds__(256) void transpose_v(const u16* __restrict__ v, u16* __restrict__ vT) {
  // v: (B,T,H*D) -> vT: (B,H,D,T); grid (B*H, D/32, T/32)
  const int bh = blockIdx.x;
  const int b = bh >> 4, h = bh & 15;
  const int d0 = blockIdx.y * 32, t0 = blockIdx.z * 32;
  __shared__ u16 tile[32][33];
  const int c = threadIdx.x & 31, r0 = threadIdx.x >> 5;
  #pragma unroll
  for (int rr = 0; rr < 32; rr += 8) {
    const int t = t0 + r0 + rr;
    tile[r0 + rr][c] = v[((size_t)b * T_ + t) * E_ + h * 64 + d0 + c];
  }
  __syncthreads();
  #pragma unroll
  for (int rr = 0; rr < 32; rr += 8) {
    const int d = d0 + r0 + rr;
    vT[((size_t)bh * D_ + d) * T_ + t0 + c] = tile[c][r0 + rr];
  }
}

__global__ __launch_bounds__(256) void transpose_echo(const float* __restrict__ e, u16* __restrict__ eT) {
  // e: (B,T,E) f32 -> eT: (B,E,T) bf16; grid (B, E/32, T/32)
  const int b = blockIdx.x;
  const int f0 = blockIdx.y * 32, t0 = blockIdx.z * 32;
  __shared__ float tile[32][33];
  const int c = threadIdx.x & 31, r0 = threadIdx.x >> 5;
  #pragma unroll
  for (int rr = 0; rr < 32; rr += 8) {
    const int t = t0 + r0 + rr;
    tile[r0 + rr][c] = e[((size_t)b * T_ + t) * E_ + f0 + c];
  }
  __syncthreads();
  #pragma unroll
  for (int rr = 0; rr < 32; rr += 8) {
    const int f = f0 + r0 + rr;
    eT[((size_t)b * E_ + f) * T_ + t0 + c] = f2bf(tile[c][r0 + rr]);
  }
}

// ---------------------------------------------------------------------------
// Gated combine: comb = g0*out1 + g1*out2 + g2*out3, g = softmax(gate[h,:])
// ---------------------------------------------------------------------------
__global__ __launch_bounds__(256) void combine_gate(
    const u16* __restrict__ o1, const u16* __restrict__ o2, const u16* __restrict__ o3,
    const float* __restrict__ gate, u16* __restrict__ comb) {
  const size_t idx = (size_t)blockIdx.x * 256 + threadIdx.x;
  const int f = (int)(idx & (E_ - 1));
  const int h = f >> 6;
  const float g0 = gate[h * 3 + 0], g1 = gate[h * 3 + 1], g2 = gate[h * 3 + 2];
  const float mx = fmaxf(g0, fmaxf(g1, g2));
  const float e0 = __expf(g0 - mx), e1 = __expf(g1 - mx), e2 = __expf(g2 - mx);
  const float inv = 1.0f / (e0 + e1 + e2);
  const float o = (e0 * bf2f(o1[idx]) + e1 * bf2f(o2[idx]) + e2 * bf2f(o3[idx])) * inv;
  comb[idx] = f2bf(o);
}

// ---------------------------------------------------------------------------
extern "C" void kernel_launch(void* const* d_in, const int* in_sizes, int n_in,
                              void* d_out, int out_size, void* d_ws, size_t ws_size,
                              hipStream_t stream) {
  (void)in_sizes; (void)n_in; (void)out_size; (void)ws_size;
  const float* x    = (const float*)d_in[0];
  const float* wq   = (const float*)d_in[1];
  const float* wk   = (const float*)d_in[2];
  const float* wv   = (const float*)d_in[3];
  const float* wvr  = (const float*)d_in[4];
  const float* wr   = (const float*)d_in[5];
  const float* wj   = (const float*)d_in[6];
  const float* gate = (const float*)d_in[7];
  const float* wo   = (const float*)d_in[8];
  float* out = (float*)d_out;

  char* p = (char*)d_ws;
  auto alloc = [&](size_t bytes) -> char* {
    char* r = p; p += (bytes + 255) & ~(size_t)255; return r;
  };
  const size_t NTE = (size_t)B_ * T_ * E_;   // 4M elements
  const size_t NW  = (size_t)E_ * E_;        // 1M elements

  u16* xb    = (u16*)alloc(NTE * 2);
  u16* xlo   = (u16*)alloc(NTE * 2);
  u16* wqb   = (u16*)alloc(NW * 2);
  u16* wkb   = (u16*)alloc(NW * 2);
  u16* wvb   = (u16*)alloc(NW * 2);
  u16* wvrb  = (u16*)alloc(NW * 2);
  u16* wjb   = (u16*)alloc(NW * 2);
  u16* wjlo  = (u16*)alloc(NW * 2);
  u16* wob   = (u16*)alloc(NW * 2);
  u16* qb    = (u16*)alloc(NTE * 2);
  u16* kb    = (u16*)alloc(NTE * 2);
  u16* vb    = (u16*)alloc(NTE * 2);
  u16* rvb   = (u16*)alloc(NTE * 2);
  u16* vT    = (u16*)alloc(NTE * 2);
  float* echoF = (float*)alloc(NTE * 4);
  u16* echoT = (u16*)alloc(NTE * 2);
  u16* a3p   = (u16*)alloc(NTE * 2);
  float* sc  = (float*)alloc((size_t)B_ * T_ * 4);
  float* s2  = (float*)alloc((size_t)B_ * H_ * T_ * 4);
  u16* wrT   = (u16*)alloc((size_t)H_ * T_ * E_ * 2);  // 32 MB
  u16* out1b = (u16*)alloc(NTE * 2);
  u16* out2b = (u16*)alloc(NTE * 2);
  u16* out3b = (u16*)alloc(NTE * 2);
  u16* comb  = (u16*)alloc(NTE * 2);
  u16* s1buf = (u16*)alloc((size_t)H_ * T_ * T_ * 2);  // per-b slab, 32 MB

  // ---- casts ----
  cast_split<<<dim3((unsigned)(NTE / 1024)), 256, 0, stream>>>(x, xb, xlo);
  cast_bf16 <<<dim3((unsigned)(NW / 1024)), 256, 0, stream>>>(wq, wqb);
  cast_bf16 <<<dim3((unsigned)(NW / 1024)), 256, 0, stream>>>(wk, wkb);
  cast_bf16 <<<dim3((unsigned)(NW / 1024)), 256, 0, stream>>>(wv, wvb);
  cast_bf16 <<<dim3((unsigned)(NW / 1024)), 256, 0, stream>>>(wvr, wvrb);
  cast_bf16 <<<dim3((unsigned)(NW / 1024)), 256, 0, stream>>>(wo, wob);
  cast_split<<<dim3((unsigned)(NW / 1024)), 256, 0, stream>>>(wj, wjb, wjlo);

  // ---- projections: (B*T,E) @ W^T ----
  const dim3 gproj(E_ / 128, (B_ * T_) / 128, 1);
  gemm_bt<2,2,4,4,false,true><<<gproj, 256, 0, stream>>>(
      xb, nullptr, wqb, nullptr, qb, E_, E_, E_, E_, E_, 0L, 0L, 0L, 1.f);
  gemm_bt<2,2,4,4,false,true><<<gproj, 256, 0, stream>>>(
      xb, nullptr, wkb, nullptr, kb, E_, E_, E_, E_, E_, 0L, 0L, 0L, 1.f);
  gemm_bt<2,2,4,4,false,true><<<gproj, 256, 0, stream>>>(
      xb, nullptr, wvb, nullptr, vb, E_, E_, E_, E_, E_, 0L, 0L, 0L, 1.f);
  gemm_bt<2,2,4,4,false,true><<<gproj, 256, 0, stream>>>(
      xb, nullptr, wvrb, nullptr, rvb, E_, E_, E_, E_, E_, 0L, 0L, 0L, 1.f);
  // echo in split-bf16 (fp32-class accuracy; feeds sc = ||echo||^2/32)
  gemm_bt<2,2,4,4,true,false><<<gproj, 256, 0, stream>>>(
      xb, xlo, wjb, wjlo, echoF, E_, E_, E_, E_, E_, 0L, 0L, 0L, 1.f);

  // ---- small/side computations ----
  transpose_v<<<dim3(B_ * H_, D_ / 32, T_ / 32), 256, 0, stream>>>(vb, vT);
  sc_kernel<<<dim3(B_ * T_), 256, 0, stream>>>(echoF, sc);
  transpose_echo<<<dim3(B_, E_ / 32, T_ / 32), 256, 0, stream>>>(echoF, echoT);
  transpose_wr<<<dim3(H_, T_ / 32, E_ / 32), 256, 0, stream>>>(wr, wrT);
  s2_fast<<<dim3(T_, B_), 256, 0, stream>>>(xb, wrT, s2);

  // ---- branch 2: parallel hierarchical prefix scan ----
  branch2_scan<<<dim3(H_, B_), 1024, 0, stream>>>(s2, rvb, out2b);

  // ---- branch 3: a3 softmax + batched GEMM out3 = a3 @ echo ----
  a3_softmax<<<dim3(T_, B_), 256, 0, stream>>>(sc, a3p);
  gemm_bt<2,2,4,4,false,true><<<dim3(E_ / 128, T_ / 128, B_), 256, 0, stream>>>(
      a3p, nullptr, echoT, nullptr, out3b, E_, T_, T_, T_, E_,
      (long)T_ * T_, (long)E_ * T_, (long)T_ * E_, 1.f);

  // ---- branch 1: per-b materialized scores (s1buf reused across b) ----
  for (int b = 0; b < B_; b++) {
    const size_t bTE = (size_t)b * T_ * E_;
    // s1[h,i,j] = q . k / 8   (batch over h via z; A,B col-offset h*64)
    gemm_bt<2,2,4,4,false,true><<<dim3(T_ / 128, T_ / 128, H_), 256, 0, stream>>>(
        qb + bTE, nullptr, kb + bTE, nullptr, s1buf, T_, D_, E_, E_, T_,
        64L, 64L, (long)T_ * T_, 0.125f);
    softmax_causal<<<dim3(T_, H_), 256, 0, stream>>>(s1buf);
    // out1[b,i,h*64+d] = a1 @ v   (N=64 narrow config)
    gemm_bt<4,1,2,4,false,true><<<dim3(1, T_ / 128, H_), 256, 0, stream>>>(
        s1buf, nullptr, vT + (size_t)b * H_ * D_ * T_, nullptr, out1b + bTE,
        D_, T_, T_, T_, E_, (long)T_ * T_, (long)D_ * T_, 64L, 1.f);
  }

  // ---- combine + output projection ----
  combine_gate<<<dim3((unsigned)(NTE / 256)), 256, 0, stream>>>(out1b, out2b, out3b, gate, comb);
  gemm_bt<2,2,4,4,false,false><<<gproj, 256, 0, stream>>>(
      comb, nullptr, wob, nullptr, out, E_, E_, E_, E_, E_, 0L, 0L, 0L, 1.f);
}

// Round 5
// 449.479 us; speedup vs baseline: 1.8187x; 1.5117x over previous
//
#include <hip/hip_runtime.h>
#include <cstdint>
#include <cstddef>

typedef unsigned short u16;
typedef short bf16x8 __attribute__((ext_vector_type(8)));
typedef float f32x4 __attribute__((ext_vector_type(4)));

constexpr int B_ = 4, T_ = 1024, E_ = 1024, H_ = 16, D_ = 64;

__device__ __forceinline__ float bf2f(u16 u) {
  union { unsigned u; float f; } v; v.u = ((unsigned)u) << 16; return v.f;
}
__device__ __forceinline__ u16 f2bf(float f) {
  union { float f; unsigned u; } v; v.f = f;
  return (u16)((v.u + 0x7fffu + ((v.u >> 16) & 1u)) >> 16);
}

#define GLD_LDS16(gp, lp)                                                      \
  __builtin_amdgcn_global_load_lds(                                            \
      (const __attribute__((address_space(1))) void*)(gp),                     \
      (__attribute__((address_space(3))) void*)(lp), 16, 0, 0)

// ---------------------------------------------------------------------------
// Tiled bf16 MFMA GEMM, C = alpha * A @ B^T.  (m97 structure; see round 0)
// ---------------------------------------------------------------------------
template<int WM, int WN, int MT, int NT, bool SPLIT, bool CBF16>
__global__ __launch_bounds__(WM * WN * 64) void gemm_bt(
    const u16* __restrict__ A, const u16* __restrict__ Alo,
    const u16* __restrict__ Bm, const u16* __restrict__ Blo,
    void* __restrict__ Cv, int N, int K,
    int lda, int ldb, int ldc,
    long batchA, long batchB, long batchC, float alpha)
{
  constexpr int TM = WM * MT * 16;
  constexpr int TN = WN * NT * 16;
  constexpr int THREADS = WM * WN * 64;
  constexpr int ASZ = TM * 32, BSZ = TN * 32;

  __shared__ u16 smem[(SPLIT ? 2 : 1) * (ASZ + BSZ)];
  u16* sA  = smem;
  u16* sB  = smem + ASZ;
  u16* sAl = smem + ASZ + BSZ;
  u16* sBl = smem + 2 * ASZ + BSZ;

  const int z = blockIdx.z;
  const u16* Ab = A + (size_t)z * batchA;
  const u16* Bb = Bm + (size_t)z * batchB;
  const int m0 = blockIdx.y * TM;
  const int n0 = blockIdx.x * TN;
  const int tid = threadIdx.x;
  const int lane = tid & 63;
  const int wave = tid >> 6;
  const int wm = wave % WM;
  const int wn = wave / WM;
  const int fr = lane & 15;   // row within 16x16 frag
  const int fg = lane >> 4;   // k-chunk (8 bf16 each)

  f32x4 acc[MT][NT];
  const f32x4 zero = {0.f, 0.f, 0.f, 0.f};
  #pragma unroll
  for (int i = 0; i < MT; i++) {
    #pragma unroll
    for (int j = 0; j < NT; j++) acc[i][j] = zero;
  }

  for (int k0 = 0; k0 < K; k0 += 32) {
    __syncthreads();   // previous tile fully consumed
    for (int s = tid; s < TM * 4; s += THREADS) {
      const int row = s >> 2, ch = s & 3;
      const size_t go = (size_t)(m0 + row) * lda + k0 + ch * 8;
      GLD_LDS16(Ab + go, &sA[s * 8]);
      if constexpr (SPLIT) GLD_LDS16(Alo + (size_t)z * batchA + go, &sAl[s * 8]);
    }
    for (int s = tid; s < TN * 4; s += THREADS) {
      const int row = s >> 2, ch = s & 3;
      int rr = n0 + row; if (rr > N - 1) rr = N - 1;  // clamp (epilogue masks cols >= N)
      const size_t go = (size_t)rr * ldb + k0 + ch * 8;
      GLD_LDS16(Bb + go, &sB[s * 8]);
      if constexpr (SPLIT) GLD_LDS16(Blo + (size_t)z * batchB + go, &sBl[s * 8]);
    }
    __syncthreads();   // drains vmcnt(0) before barrier (m97 semantics)

    bf16x8 av[MT], bv[NT];
    #pragma unroll
    for (int mt = 0; mt < MT; mt++)
      av[mt] = *(const bf16x8*)&sA[((wm * MT + mt) * 16 + fr) * 32 + fg * 8];
    #pragma unroll
    for (int nt = 0; nt < NT; nt++)
      bv[nt] = *(const bf16x8*)&sB[((wn * NT + nt) * 16 + fr) * 32 + fg * 8];
    #pragma unroll
    for (int mt = 0; mt < MT; mt++) {
      #pragma unroll
      for (int nt = 0; nt < NT; nt++)
        acc[mt][nt] = __builtin_amdgcn_mfma_f32_16x16x32_bf16(av[mt], bv[nt], acc[mt][nt], 0, 0, 0);
    }
    if constexpr (SPLIT) {
      bf16x8 al[MT], bl[NT];
      #pragma unroll
      for (int mt = 0; mt < MT; mt++)
        al[mt] = *(const bf16x8*)&sAl[((wm * MT + mt) * 16 + fr) * 32 + fg * 8];
      #pragma unroll
      for (int nt = 0; nt < NT; nt++)
        bl[nt] = *(const bf16x8*)&sBl[((wn * NT + nt) * 16 + fr) * 32 + fg * 8];
      #pragma unroll
      for (int mt = 0; mt < MT; mt++) {
        #pragma unroll
        for (int nt = 0; nt < NT; nt++) {
          acc[mt][nt] = __builtin_amdgcn_mfma_f32_16x16x32_bf16(al[mt], bv[nt], acc[mt][nt], 0, 0, 0);
          acc[mt][nt] = __builtin_amdgcn_mfma_f32_16x16x32_bf16(av[mt], bl[nt], acc[mt][nt], 0, 0, 0);
        }
      }
    }
  }

  // epilogue: C/D layout col = lane&15, row = (lane>>4)*4 + reg (m89-verified)
  const int er = (lane >> 4) * 4;
  const int ec = lane & 15;
  #pragma unroll
  for (int mt = 0; mt < MT; mt++) {
    #pragma unroll
    for (int nt = 0; nt < NT; nt++) {
      const int row = m0 + (wm * MT + mt) * 16 + er;
      const int col = n0 + (wn * NT + nt) * 16 + ec;
      if (col < N) {
        #pragma unroll
        for (int r2 = 0; r2 < 4; r2++) {
          const float vv = acc[mt][nt][r2] * alpha;
          const size_t ci = (size_t)z * batchC + (size_t)(row + r2) * ldc + col;
          if constexpr (CBF16) ((u16*)Cv)[ci] = f2bf(vv);
          else                 ((float*)Cv)[ci] = vv;
        }
      }
    }
  }
}

// ---------------------------------------------------------------------------
// Flash-fused branch 1: per (i-tile 128, h, b). Q,K from qkvr (ld 4096),
// V^T from vT (B,H,D,T). Online softmax; P via per-wave-private LDS rows
// (no extra barrier). out1 = softmax(QK^T/8, causal) @ V, bf16.
// ---------------------------------------------------------------------------
__global__ __launch_bounds__(256, 2) void flash1(
    const u16* __restrict__ qkvr, const u16* __restrict__ vT, u16* __restrict__ out1) {
  const int it = blockIdx.x, h = blockIdx.y, b = blockIdx.z;
  const int tid = threadIdx.x, lane = tid & 63, w = tid >> 6;
  const int fr = lane & 15, fg = lane >> 4;

  __shared__ u16 sQ[128 * 64];    // 16 KB
  __shared__ u16 sK[128 * 64];    // 16 KB
  __shared__ u16 sVt[64 * 128];   // 16 KB  (d-major: row d, col j)
  __shared__ u16 sP[128 * 128];   // 32 KB  (per-wave-private 32-row bands)

  const u16* Qb = qkvr + ((size_t)(b * T_) + it * 128) * 4096 + h * 64;
  const u16* Kb = qkvr + (size_t)(b * T_) * 4096 + 1024 + h * 64;
  const u16* Vb = vT + (size_t)(b * H_ + h) * (D_ * T_);

  // stage Q once: 128 rows x 64 cols = 1024 x 16B chunks (8 chunks/row)
  for (int s = tid; s < 1024; s += 256)
    GLD_LDS16(Qb + (size_t)(s >> 3) * 4096 + (s & 7) * 8, &sQ[s * 8]);

  f32x4 accO[2][4];
  float mrow[2][4], lrow[2][4];
  #pragma unroll
  for (int mf = 0; mf < 2; mf++)
    #pragma unroll
    for (int r = 0; r < 4; r++) {
      mrow[mf][r] = -3.0e38f; lrow[mf][r] = 0.f;
    }
  #pragma unroll
  for (int mf = 0; mf < 2; mf++)
    #pragma unroll
    for (int nf = 0; nf < 4; nf++) accO[mf][nf] = f32x4{0.f, 0.f, 0.f, 0.f};

  for (int jt = 0; jt <= it; jt++) {
    __syncthreads();   // prior K/Vt fully consumed (also orders Q staging)
    for (int s = tid; s < 1024; s += 256)
      GLD_LDS16(Kb + (size_t)(jt * 128 + (s >> 3)) * 4096 + (s & 7) * 8, &sK[s * 8]);
    for (int s = tid; s < 1024; s += 256)
      GLD_LDS16(Vb + (size_t)(s >> 4) * T_ + jt * 128 + (s & 15) * 8, &sVt[s * 8]);
    __syncthreads();

    // ---- S = Q @ K^T ----
    bf16x8 aQ[2][2];
    #pragma unroll
    for (int mf = 0; mf < 2; mf++)
      #pragma unroll
      for (int kk = 0; kk < 2; kk++)
        aQ[mf][kk] = *(const bf16x8*)&sQ[(w * 32 + mf * 16 + fr) * 64 + kk * 32 + fg * 8];

    f32x4 accS[2][8];
    #pragma unroll
    for (int mf = 0; mf < 2; mf++)
      #pragma unroll
      for (int nf = 0; nf < 8; nf++) accS[mf][nf] = f32x4{0.f, 0.f, 0.f, 0.f};
    #pragma unroll
    for (int nf = 0; nf < 8; nf++) {
      #pragma unroll
      for (int kk = 0; kk < 2; kk++) {
        const bf16x8 bK = *(const bf16x8*)&sK[(nf * 16 + fr) * 64 + kk * 32 + fg * 8];
        accS[0][nf] = __builtin_amdgcn_mfma_f32_16x16x32_bf16(aQ[0][kk], bK, accS[0][nf], 0, 0, 0);
        accS[1][nf] = __builtin_amdgcn_mfma_f32_16x16x32_bf16(aQ[1][kk], bK, accS[1][nf], 0, 0, 0);
      }
    }

    // ---- online softmax (rows owned: w*32 + mf*16 + fg*4 + r) ----
    const bool diag = (jt == it);
    #pragma unroll
    for (int mf = 0; mf < 2; mf++) {
      #pragma unroll
      for (int r = 0; r < 4; r++) {
        const int rloc = w * 32 + mf * 16 + fg * 4 + r;
        float sv[8];
        float rmax = -3.0e38f;
        #pragma unroll
        for (int nf = 0; nf < 8; nf++) {
          float s = accS[mf][nf][r] * 0.125f;
          if (diag && (nf * 16 + fr) > rloc) s = -3.0e38f;
          sv[nf] = s;
          rmax = fmaxf(rmax, s);
        }
        #pragma unroll
        for (int mk = 8; mk > 0; mk >>= 1) rmax = fmaxf(rmax, __shfl_xor(rmax, mk, 64));
        const float mn = fmaxf(mrow[mf][r], rmax);
        const float alpha = __expf(mrow[mf][r] - mn);
        mrow[mf][r] = mn;
        float psum = 0.f;
        #pragma unroll
        for (int nf = 0; nf < 8; nf++) {
          const float pv = __expf(sv[nf] - mn);
          psum += pv;
          sP[(size_t)rloc * 128 + nf * 16 + fr] = f2bf(pv);
        }
        #pragma unroll
        for (int mk = 8; mk > 0; mk >>= 1) psum += __shfl_xor(psum, mk, 64);
        lrow[mf][r] = lrow[mf][r] * alpha + psum;
        #pragma unroll
        for (int nf2 = 0; nf2 < 4; nf2++) accO[mf][nf2][r] *= alpha;
      }
    }

    // ---- O += P @ V  (A-frags from own sP band; B-frags from sVt) ----
    #pragma unroll
    for (int kk = 0; kk < 4; kk++) {
      bf16x8 aP[2];
      aP[0] = *(const bf16x8*)&sP[(w * 32 + fr) * 128 + kk * 32 + fg * 8];
      aP[1] = *(const bf16x8*)&sP[(w * 32 + 16 + fr) * 128 + kk * 32 + fg * 8];
      #pragma unroll
      for (int nf2 = 0; nf2 < 4; nf2++) {
        const bf16x8 bV = *(const bf16x8*)&sVt[(nf2 * 16 + fr) * 128 + kk * 32 + fg * 8];
        accO[0][nf2] = __builtin_amdgcn_mfma_f32_16x16x32_bf16(aP[0], bV, accO[0][nf2], 0, 0, 0);
        accO[1][nf2] = __builtin_amdgcn_mfma_f32_16x16x32_bf16(aP[1], bV, accO[1][nf2], 0, 0, 0);
      }
    }
  }

  // ---- epilogue: out1[b, i, h*64+d] = O / l ----
  u16* op = out1 + ((size_t)(b * T_) + it * 128) * E_ + h * 64;
  #pragma unroll
  for (int mf = 0; mf < 2; mf++) {
    #pragma unroll
    for (int r = 0; r < 4; r++) {
      const float inv = 1.0f / lrow[mf][r];
      const int row = w * 32 + mf * 16 + fg * 4 + r;
      #pragma unroll
      for (int nf2 = 0; nf2 < 4; nf2++)
        op[(size_t)row * E_ + nf2 * 16 + fr] = f2bf(accO[mf][nf2][r] * inv);
    }
  }
}

// ---------------------------------------------------------------------------
// Reductions (256-thread blocks, 4 waves)
// ---------------------------------------------------------------------------
__device__ __forceinline__ float block_max256(float v, float* red) {
  #pragma unroll
  for (int m = 32; m > 0; m >>= 1) v = fmaxf(v, __shfl_xor(v, m, 64));
  if ((threadIdx.x & 63) == 0) red[threadIdx.x >> 6] = v;
  __syncthreads();
  const float r = fmaxf(fmaxf(red[0], red[1]), fmaxf(red[2], red[3]));
  __syncthreads();
  return r;
}
__device__ __forceinline__ float block_sum256(float v, float* red) {
  #pragma unroll
  for (int m = 32; m > 0; m >>= 1) v += __shfl_xor(v, m, 64);
  if ((threadIdx.x & 63) == 0) red[threadIdx.x >> 6] = v;
  __syncthreads();
  const float r = (red[0] + red[1]) + (red[2] + red[3]);
  __syncthreads();
  return r;
}

// ---------------------------------------------------------------------------
// Casts
// ---------------------------------------------------------------------------
__global__ __launch_bounds__(256) void cast_bf16(const float* __restrict__ in, u16* __restrict__ out) {
  const size_t i = ((size_t)blockIdx.x * 256 + threadIdx.x) * 4;
  const float4 v = *(const float4*)(in + i);
  ushort4 o;
  o.x = f2bf(v.x); o.y = f2bf(v.y); o.z = f2bf(v.z); o.w = f2bf(v.w);
  *(ushort4*)(out + i) = o;
}
__global__ __launch_bounds__(256) void cast_split(const float* __restrict__ in,
                                                  u16* __restrict__ hi, u16* __restrict__ lo) {
  const size_t i = ((size_t)blockIdx.x * 256 + threadIdx.x) * 4;
  const float4 v = *(const float4*)(in + i);
  ushort4 oh, ol;
  oh.x = f2bf(v.x); ol.x = f2bf(v.x - bf2f(oh.x));
  oh.y = f2bf(v.y); ol.y = f2bf(v.y - bf2f(oh.y));
  oh.z = f2bf(v.z); ol.z = f2bf(v.z - bf2f(oh.z));
  oh.w = f2bf(v.w); ol.w = f2bf(v.w - bf2f(oh.w));
  *(ushort4*)(hi + i) = oh;
  *(ushort4*)(lo + i) = ol;
}

// ---------------------------------------------------------------------------
// sc[b,t] = ||echo[b,t,:]||^2 / 32   (echo_back GEMM eliminated algebraically)
// ---------------------------------------------------------------------------
__global__ __launch_bounds__(256) void sc_kernel(const float* __restrict__ echo, float* __restrict__ sc) {
  const int row = blockIdx.x;
  const float4 v = ((const float4*)(echo + (size_t)row * E_))[threadIdx.x];
  float ss = v.x * v.x + v.y * v.y + v.z * v.z + v.w * v.w;
  __shared__ float red[4];
  ss = block_sum256(ss, red);
  if (threadIdx.x == 0) sc[row] = ss * (1.0f / 32.0f);
}

// ---------------------------------------------------------------------------
// transpose_wr: wr (H,E,T) f32 -> wrT (H,T,E) bf16; grid (H, T/32, E/32)
// ---------------------------------------------------------------------------
__global__ __launch_bounds__(256) void transpose_wr(const float* __restrict__ wr, u16* __restrict__ wrT) {
  const int h = blockIdx.x;
  const int t0 = blockIdx.y * 32, e0 = blockIdx.z * 32;
  __shared__ float tile[32][33];
  const int c = threadIdx.x & 31, r0 = threadIdx.x >> 5;
  #pragma unroll
  for (int rr = 0; rr < 32; rr += 8) {
    const int e = e0 + r0 + rr;
    tile[r0 + rr][c] = wr[((size_t)h * E_ + e) * T_ + t0 + c];   // coalesced in t
  }
  __syncthreads();
  #pragma unroll
  for (int rr = 0; rr < 32; rr += 8) {
    const int t = t0 + r0 + rr;
    wrT[((size_t)h * T_ + t) * E_ + e0 + c] = f2bf(tile[c][r0 + rr]);  // coalesced in e
  }
}

// ---------------------------------------------------------------------------
// s2_fast: s2[b,h,t] = dot(xb[b,t,:], wrT[h,t,:]) / 8.
// ---------------------------------------------------------------------------
__global__ __launch_bounds__(256) void s2_fast(
    const u16* __restrict__ xb, const u16* __restrict__ wrT, float* __restrict__ s2) {
  const int t = blockIdx.x, b = blockIdx.y;
  const int lane = threadIdx.x & 63;
  const int wv = threadIdx.x >> 6;
  const u16* xr = xb + ((size_t)b * T_ + t) * E_ + lane * 16;
  const bf16x8 xv0 = *(const bf16x8*)xr;
  const bf16x8 xv1 = *(const bf16x8*)(xr + 8);
  #pragma unroll
  for (int hh = 0; hh < 4; hh++) {
    const int h = wv + hh * 4;
    const u16* wp = wrT + ((size_t)h * T_ + t) * E_ + lane * 16;
    const bf16x8 w0 = *(const bf16x8*)wp;
    const bf16x8 w1 = *(const bf16x8*)(wp + 8);
    float acc = 0.f;
    #pragma unroll
    for (int i2 = 0; i2 < 8; i2++) {
      acc += bf2f((u16)xv0[i2]) * bf2f((u16)w0[i2]);
      acc += bf2f((u16)xv1[i2]) * bf2f((u16)w1[i2]);
    }
    #pragma unroll
    for (int mk = 32; mk > 0; mk >>= 1) acc += __shfl_xor(acc, mk, 64);
    if (lane == 0) s2[((size_t)b * H_ + h) * T_ + t] = acc * 0.125f;
  }
}

// ---------------------------------------------------------------------------
// a3[b,i,j] = softmax_{j<=i}(sc_i*sc_j), written bf16 (zeros above diagonal)
// ---------------------------------------------------------------------------
__global__ __launch_bounds__(256) void a3_softmax(const float* __restrict__ sc, u16* __restrict__ a3) {
  const int i = blockIdx.x;
  const int b = blockIdx.y;
  const float* sr = sc + (size_t)b * T_;
  const float sci = sr[i];
  u16* row = a3 + ((size_t)b * T_ + i) * T_;
  __shared__ float red[4];
  float v[4];
  float m = -3.0e38f;
  #pragma unroll
  for (int k = 0; k < 4; k++) {
    const int j = threadIdx.x + k * 256;
    const float xv = (j <= i) ? sci * sr[j] : -3.0e38f;
    v[k] = xv;
    m = fmaxf(m, xv);
  }
  m = block_max256(m, red);
  float s = 0.f;
  #pragma unroll
  for (int k = 0; k < 4; k++) {
    const int j = threadIdx.x + k * 256;
    const float p = (j <= i) ? __expf(v[k] - m) : 0.f;
    v[k] = p;
    s += p;
  }
  s = block_sum256(s, red);
  const float inv = 1.0f / s;
  #pragma unroll
  for (int k = 0; k < 4; k++) {
    const int j = threadIdx.x + k * 256;
    row[j] = f2bf(v[k] * inv);
  }
}

// ---------------------------------------------------------------------------
// Branch 2: broadcast-key softmax => prefix scan, parallelized (round-1 win).
// rv is a strided view (row stride ldrv) into qkvr.
// ---------------------------------------------------------------------------
__global__ __launch_bounds__(1024) void branch2_scan(
    const float* __restrict__ s2, const u16* __restrict__ rv, int ldrv,
    u16* __restrict__ out2) {
  const int h = blockIdx.x, b = blockIdx.y;
  const int tid = threadIdx.x;
  const int lane = tid & 63;   // d
  const int wv = tid >> 6;     // j-chunk index, 0..15

  const float* srow = s2 + ((size_t)b * H_ + h) * T_;

  __shared__ float wbuf[T_];
  __shared__ float numtot[16][64];
  __shared__ float dentot[16];
  __shared__ float redm[16];

  float m = srow[tid];
  #pragma unroll
  for (int mk = 32; mk > 0; mk >>= 1) m = fmaxf(m, __shfl_xor(m, mk, 64));
  if (lane == 0) redm[wv] = m;
  __syncthreads();
  m = redm[0];
  #pragma unroll
  for (int i2 = 1; i2 < 16; i2++) m = fmaxf(m, redm[i2]);

  wbuf[tid] = __expf(srow[tid] - m);
  __syncthreads();

  const u16* rvp = rv + (size_t)(b * T_) * ldrv + h * D_ + lane;
  const int j0 = wv * 64;
  float num = 0.f, den = 0.f;
  #pragma unroll 8
  for (int j2 = 0; j2 < 64; j2++) {
    const float w = wbuf[j0 + j2];
    den += w;
    num += w * bf2f(rvp[(size_t)(j0 + j2) * ldrv]);
  }
  numtot[wv][lane] = num;
  if (lane == 0) dentot[wv] = den;
  __syncthreads();

  float num_off = 0.f, den_off = 0.f;
  for (int w2 = 0; w2 < wv; w2++) {
    num_off += numtot[w2][lane];
    den_off += dentot[w2];
  }

  u16* op = out2 + (size_t)b * T_ * E_ + h * D_ + lane;
  num = num_off; den = den_off;
  #pragma unroll 8
  for (int j2 = 0; j2 < 64; j2++) {
    const float w = wbuf[j0 + j2];
    num += w * bf2f(rvp[(size_t)(j0 + j2) * ldrv]);
    den += w;
    op[(size_t)(j0 + j2) * E_] = f2bf(num / den);
  }
}

// ---------------------------------------------------------------------------
// Transposes
// ---------------------------------------------------------------------------
__global__ __launch_bounds__(256) void transpose_v(const u16* __restrict__ v, u16* __restrict__ vT,
                                                   int ldv) {
  // v view: rows (b*T+t), cols h*64+d at row stride ldv -> vT: (B,H,D,T)
  const int bh = blockIdx.x;
  const int b = bh >> 4, h = bh & 15;
  const int d0 = blockIdx.y * 32, t0 = blockIdx.z * 32;
  __shared__ u16 tile[32][33];
  const int c = threadIdx.x & 31, r0 = threadIdx.x >> 5;
  #pragma unroll
  for (int rr = 0; rr < 32; rr += 8) {
    const int t = t0 + r0 + rr;
    tile[r0 + rr][c] = v[((size_t)b * T_ + t) * ldv + h * 64 + d0 + c];
  }
  __syncthreads();
  #pragma unroll
  for (int rr = 0; rr < 32; rr += 8) {
    const int d = d0 + r0 + rr;
    vT[((size_t)bh * D_ + d) * T_ + t0 + c] = tile[c][r0 + rr];
  }
}

__global__ __launch_bounds__(256) void transpose_echo(const float* __restrict__ e, u16* __restrict__ eT) {
  const int b = blockIdx.x;
  const int f0 = blockIdx.y * 32, t0 = blockIdx.z * 32;
  __shared__ float tile[32][33];
  const int c = threadIdx.x & 31, r0 = threadIdx.x >> 5;
  #pragma unroll
  for (int rr = 0; rr < 32; rr += 8) {
    const int t = t0 + r0 + rr;
    tile[r0 + rr][c] = e[((size_t)b * T_ + t) * E_ + f0 + c];
  }
  __syncthreads();
  #pragma unroll
  for (int rr = 0; rr < 32; rr += 8) {
    const int f = f0 + r0 + rr;
    eT[((size_t)b * E_ + f) * T_ + t0 + c] = f2bf(tile[c][r0 + rr]);
  }
}

// ---------------------------------------------------------------------------
// Gated combine
// ---------------------------------------------------------------------------
__global__ __launch_bounds__(256) void combine_gate(
    const u16* __restrict__ o1, const u16* __restrict__ o2, const u16* __restrict__ o3,
    const float* __restrict__ gate, u16* __restrict__ comb) {
  const size_t idx = (size_t)blockIdx.x * 256 + threadIdx.x;
  const int f = (int)(idx & (E_ - 1));
  const int h = f >> 6;
  const float g0 = gate[h * 3 + 0], g1 = gate[h * 3 + 1], g2 = gate[h * 3 + 2];
  const float mx = fmaxf(g0, fmaxf(g1, g2));
  const float e0 = __expf(g0 - mx), e1 = __expf(g1 - mx), e2 = __expf(g2 - mx);
  const float inv = 1.0f / (e0 + e1 + e2);
  const float o = (e0 * bf2f(o1[idx]) + e1 * bf2f(o2[idx]) + e2 * bf2f(o3[idx])) * inv;
  comb[idx] = f2bf(o);
}

// ---------------------------------------------------------------------------
extern "C" void kernel_launch(void* const* d_in, const int* in_sizes, int n_in,
                              void* d_out, int out_size, void* d_ws, size_t ws_size,
                              hipStream_t stream) {
  (void)in_sizes; (void)n_in; (void)out_size; (void)ws_size;
  const float* x    = (const float*)d_in[0];
  const float* wq   = (const float*)d_in[1];
  const float* wk   = (const float*)d_in[2];
  const float* wv   = (const float*)d_in[3];
  const float* wvr  = (const float*)d_in[4];
  const float* wr   = (const float*)d_in[5];
  const float* wj   = (const float*)d_in[6];
  const float* gate = (const float*)d_in[7];
  const float* wo   = (const float*)d_in[8];
  float* out = (float*)d_out;

  char* p = (char*)d_ws;
  auto alloc = [&](size_t bytes) -> char* {
    char* r = p; p += (bytes + 255) & ~(size_t)255; return r;
  };
  const size_t NTE = (size_t)B_ * T_ * E_;   // 4M elements
  const size_t NW  = (size_t)E_ * E_;        // 1M elements

  u16* xb    = (u16*)alloc(NTE * 2);
  u16* xlo   = (u16*)alloc(NTE * 2);
  u16* wcat  = (u16*)alloc(4 * NW * 2);      // [wq; wk; wv; wvr] rows
  u16* wjb   = (u16*)alloc(NW * 2);
  u16* wjlo  = (u16*)alloc(NW * 2);
  u16* wob   = (u16*)alloc(NW * 2);
  u16* qkvr  = (u16*)alloc(NTE * 4 * 2);     // (B*T, 4096): q|k|v|rv
  u16* vT    = (u16*)alloc(NTE * 2);
  float* echoF = (float*)alloc(NTE * 4);
  u16* echoT = (u16*)alloc(NTE * 2);
  u16* a3p   = (u16*)alloc(NTE * 2);
  float* sc  = (float*)alloc((size_t)B_ * T_ * 4);
  float* s2  = (float*)alloc((size_t)B_ * H_ * T_ * 4);
  u16* wrT   = (u16*)alloc((size_t)H_ * T_ * E_ * 2);
  u16* out1b = (u16*)alloc(NTE * 2);
  u16* out2b = (u16*)alloc(NTE * 2);
  u16* out3b = (u16*)alloc(NTE * 2);
  u16* comb  = (u16*)alloc(NTE * 2);

  // ---- casts ----
  cast_split<<<dim3((unsigned)(NTE / 1024)), 256, 0, stream>>>(x, xb, xlo);
  cast_bf16 <<<dim3((unsigned)(NW / 1024)), 256, 0, stream>>>(wq, wcat);
  cast_bf16 <<<dim3((unsigned)(NW / 1024)), 256, 0, stream>>>(wk, wcat + NW);
  cast_bf16 <<<dim3((unsigned)(NW / 1024)), 256, 0, stream>>>(wv, wcat + 2 * NW);
  cast_bf16 <<<dim3((unsigned)(NW / 1024)), 256, 0, stream>>>(wvr, wcat + 3 * NW);
  cast_bf16 <<<dim3((unsigned)(NW / 1024)), 256, 0, stream>>>(wo, wob);
  cast_split<<<dim3((unsigned)(NW / 1024)), 256, 0, stream>>>(wj, wjb, wjlo);

  // ---- fused q|k|v|rv projection: (B*T,1024) @ (4096,1024)^T -> (B*T,4096) ----
  gemm_bt<2,2,4,4,false,true><<<dim3(32, 32, 1), 256, 0, stream>>>(
      xb, nullptr, wcat, nullptr, qkvr, 4096, E_, E_, E_, 4096, 0L, 0L, 0L, 1.f);

  // ---- echo in split-bf16, 128x64 tiles for 2 blocks/CU ----
  gemm_bt<2,2,4,2,true,false><<<dim3(16, 32, 1), 256, 0, stream>>>(
      xb, xlo, wjb, wjlo, echoF, E_, E_, E_, E_, E_, 0L, 0L, 0L, 1.f);

  // ---- side computations ----
  transpose_v<<<dim3(B_ * H_, D_ / 32, T_ / 32), 256, 0, stream>>>(qkvr + 2048, vT, 4096);
  sc_kernel<<<dim3(B_ * T_), 256, 0, stream>>>(echoF, sc);
  transpose_echo<<<dim3(B_, E_ / 32, T_ / 32), 256, 0, stream>>>(echoF, echoT);
  transpose_wr<<<dim3(H_, T_ / 32, E_ / 32), 256, 0, stream>>>(wr, wrT);
  s2_fast<<<dim3(T_, B_), 256, 0, stream>>>(xb, wrT, s2);

  // ---- branch 2 ----
  branch2_scan<<<dim3(H_, B_), 1024, 0, stream>>>(s2, qkvr + 3072, 4096, out2b);

  // ---- branch 3 ----
  a3_softmax<<<dim3(T_, B_), 256, 0, stream>>>(sc, a3p);
  gemm_bt<2,2,4,4,false,true><<<dim3(E_ / 128, T_ / 128, B_), 256, 0, stream>>>(
      a3p, nullptr, echoT, nullptr, out3b, E_, T_, T_, T_, E_,
      (long)T_ * T_, (long)E_ * T_, (long)T_ * E_, 1.f);

  // ---- branch 1: flash-fused ----
  flash1<<<dim3(T_ / 128, H_, B_), 256, 0, stream>>>(qkvr, vT, out1b);

  // ---- combine + output projection ----
  combine_gate<<<dim3((unsigned)(NTE / 256)), 256, 0, stream>>>(out1b, out2b, out3b, gate, comb);
  gemm_bt<2,2,4,4,false,false><<<dim3(E_ / 128, (B_ * T_) / 128, 1), 256, 0, stream>>>(
      comb, nullptr, wob, nullptr, out, E_, E_, E_, E_, E_, 0L, 0L, 0L, 1.f);
}

// Round 6
// 426.199 us; speedup vs baseline: 1.9180x; 1.0546x over previous
//
#include <hip/hip_runtime.h>
#include <cstdint>
#include <cstddef>

typedef unsigned short u16;
typedef short bf16x8 __attribute__((ext_vector_type(8)));
typedef short bf16x4 __attribute__((ext_vector_type(4)));
typedef float f32x4 __attribute__((ext_vector_type(4)));

constexpr int B_ = 4, T_ = 1024, E_ = 1024, H_ = 16, D_ = 64;

__device__ __forceinline__ float bf2f(u16 u) {
  union { unsigned u; float f; } v; v.u = ((unsigned)u) << 16; return v.f;
}
__device__ __forceinline__ u16 f2bf(float f) {
  union { float f; unsigned u; } v; v.f = f;
  return (u16)((v.u + 0x7fffu + ((v.u >> 16) & 1u)) >> 16);
}

#define GLD_LDS16(gp, lp)                                                      \
  __builtin_amdgcn_global_load_lds(                                            \
      (const __attribute__((address_space(1))) void*)(gp),                     \
      (__attribute__((address_space(3))) void*)(lp), 16, 0, 0)

// ---------------------------------------------------------------------------
// Tiled bf16 MFMA GEMM, C = alpha * A @ B^T.  (m97 structure; see round 0)
// ---------------------------------------------------------------------------
template<int WM, int WN, int MT, int NT, bool SPLIT, bool CBF16>
__global__ __launch_bounds__(WM * WN * 64) void gemm_bt(
    const u16* __restrict__ A, const u16* __restrict__ Alo,
    const u16* __restrict__ Bm, const u16* __restrict__ Blo,
    void* __restrict__ Cv, int N, int K,
    int lda, int ldb, int ldc,
    long batchA, long batchB, long batchC, float alpha)
{
  constexpr int TM = WM * MT * 16;
  constexpr int TN = WN * NT * 16;
  constexpr int THREADS = WM * WN * 64;
  constexpr int ASZ = TM * 32, BSZ = TN * 32;

  __shared__ u16 smem[(SPLIT ? 2 : 1) * (ASZ + BSZ)];
  u16* sA  = smem;
  u16* sB  = smem + ASZ;
  u16* sAl = smem + ASZ + BSZ;
  u16* sBl = smem + 2 * ASZ + BSZ;

  const int z = blockIdx.z;
  const u16* Ab = A + (size_t)z * batchA;
  const u16* Bb = Bm + (size_t)z * batchB;
  const int m0 = blockIdx.y * TM;
  const int n0 = blockIdx.x * TN;
  const int tid = threadIdx.x;
  const int lane = tid & 63;
  const int wave = tid >> 6;
  const int wm = wave % WM;
  const int wn = wave / WM;
  const int fr = lane & 15;   // row within 16x16 frag
  const int fg = lane >> 4;   // k-chunk (8 bf16 each)

  f32x4 acc[MT][NT];
  const f32x4 zero = {0.f, 0.f, 0.f, 0.f};
  #pragma unroll
  for (int i = 0; i < MT; i++) {
    #pragma unroll
    for (int j = 0; j < NT; j++) acc[i][j] = zero;
  }

  for (int k0 = 0; k0 < K; k0 += 32) {
    __syncthreads();   // previous tile fully consumed
    for (int s = tid; s < TM * 4; s += THREADS) {
      const int row = s >> 2, ch = s & 3;
      const size_t go = (size_t)(m0 + row) * lda + k0 + ch * 8;
      GLD_LDS16(Ab + go, &sA[s * 8]);
      if constexpr (SPLIT) GLD_LDS16(Alo + (size_t)z * batchA + go, &sAl[s * 8]);
    }
    for (int s = tid; s < TN * 4; s += THREADS) {
      const int row = s >> 2, ch = s & 3;
      int rr = n0 + row; if (rr > N - 1) rr = N - 1;  // clamp (epilogue masks cols >= N)
      const size_t go = (size_t)rr * ldb + k0 + ch * 8;
      GLD_LDS16(Bb + go, &sB[s * 8]);
      if constexpr (SPLIT) GLD_LDS16(Blo + (size_t)z * batchB + go, &sBl[s * 8]);
    }
    __syncthreads();   // drains vmcnt(0) before barrier (m97 semantics)

    bf16x8 av[MT], bv[NT];
    #pragma unroll
    for (int mt = 0; mt < MT; mt++)
      av[mt] = *(const bf16x8*)&sA[((wm * MT + mt) * 16 + fr) * 32 + fg * 8];
    #pragma unroll
    for (int nt = 0; nt < NT; nt++)
      bv[nt] = *(const bf16x8*)&sB[((wn * NT + nt) * 16 + fr) * 32 + fg * 8];
    #pragma unroll
    for (int mt = 0; mt < MT; mt++) {
      #pragma unroll
      for (int nt = 0; nt < NT; nt++)
        acc[mt][nt] = __builtin_amdgcn_mfma_f32_16x16x32_bf16(av[mt], bv[nt], acc[mt][nt], 0, 0, 0);
    }
    if constexpr (SPLIT) {
      bf16x8 al[MT], bl[NT];
      #pragma unroll
      for (int mt = 0; mt < MT; mt++)
        al[mt] = *(const bf16x8*)&sAl[((wm * MT + mt) * 16 + fr) * 32 + fg * 8];
      #pragma unroll
      for (int nt = 0; nt < NT; nt++)
        bl[nt] = *(const bf16x8*)&sBl[((wn * NT + nt) * 16 + fr) * 32 + fg * 8];
      #pragma unroll
      for (int mt = 0; mt < MT; mt++) {
        #pragma unroll
        for (int nt = 0; nt < NT; nt++) {
          acc[mt][nt] = __builtin_amdgcn_mfma_f32_16x16x32_bf16(al[mt], bv[nt], acc[mt][nt], 0, 0, 0);
          acc[mt][nt] = __builtin_amdgcn_mfma_f32_16x16x32_bf16(av[mt], bl[nt], acc[mt][nt], 0, 0, 0);
        }
      }
    }
  }

  // epilogue: C/D layout col = lane&15, row = (lane>>4)*4 + reg (m89-verified)
  const int er = (lane >> 4) * 4;
  const int ec = lane & 15;
  #pragma unroll
  for (int mt = 0; mt < MT; mt++) {
    #pragma unroll
    for (int nt = 0; nt < NT; nt++) {
      const int row = m0 + (wm * MT + mt) * 16 + er;
      const int col = n0 + (wn * NT + nt) * 16 + ec;
      if (col < N) {
        #pragma unroll
        for (int r2 = 0; r2 < 4; r2++) {
          const float vv = acc[mt][nt][r2] * alpha;
          const size_t ci = (size_t)z * batchC + (size_t)(row + r2) * ldc + col;
          if constexpr (CBF16) ((u16*)Cv)[ci] = f2bf(vv);
          else                 ((float*)Cv)[ci] = vv;
        }
      }
    }
  }
}

// ---------------------------------------------------------------------------
// Flash-fused branch 1, register-resident (no P round-trip through LDS).
// Computes S^T = K@Q^T so P lands directly in A-operand k-slot layout:
// accST frag nf reg r holds S(i = w*32+mf*16+fr, j = nf*16+fg*4+r).
// PV uses zero-padded 16x16x32 MFMA (real values in jj 0..3 of BOTH A and B
// at k-slot fg*8+jj -> exact dot product over the 16 real j's per frag).
// sQ/sK staged fragment-major (slot = frag*64+lane): stride-1 b128 reads,
// conflict-free, GLD-affine. V staged from blocked vT' (t8,d,8) layout.
// LDS 48 KB.
// ---------------------------------------------------------------------------
__global__ __launch_bounds__(256, 2) void flash1(
    const u16* __restrict__ qkvr, const u16* __restrict__ vTb, u16* __restrict__ out1) {
  const int it = blockIdx.x, h = blockIdx.y, b = blockIdx.z;
  const int tid = threadIdx.x, lane = tid & 63, w = tid >> 6;
  const int fr = lane & 15, fg = lane >> 4;

  __shared__ u16 sQ[8192];   // frag-major: slot g*64+l, g = row16*2+kk
  __shared__ u16 sK[8192];
  __shared__ u16 sV[8192];   // blocked: slot jc*64+d holds V(d, j=jc*8..jc*8+7)

  const u16* Qb = qkvr + ((size_t)(b * T_) + it * 128) * 4096 + h * 64;
  const u16* Kb = qkvr + (size_t)(b * T_) * 4096 + 1024 + h * 64;
  const u16* Vb = vTb + (size_t)(b * H_ + h) * (D_ * T_);

  // ---- stage Q once, fragment-major ----
  for (int s = tid; s < 1024; s += 256) {
    const int l = s & 63, g = s >> 6;
    const int row = (g >> 1) * 16 + (l & 15);
    const int c8  = (g & 1) * 4 + (l >> 4);
    GLD_LDS16(Qb + (size_t)row * 4096 + c8 * 8, &sQ[s * 8]);
  }
  __syncthreads();

  // Q as B-operand frags (n = i, k = d): row i = w*32 + mf*16 + fr
  bf16x8 bQ[2][2];
  #pragma unroll
  for (int mf = 0; mf < 2; mf++)
    #pragma unroll
    for (int kk = 0; kk < 2; kk++)
      bQ[mf][kk] = *(const bf16x8*)&sQ[((((w * 2 + mf) * 2 + kk) << 6) | lane) * 8];

  f32x4 accO[2][4];
  float mrow[2], lrow[2];
  #pragma unroll
  for (int mf = 0; mf < 2; mf++) {
    mrow[mf] = -3.0e38f; lrow[mf] = 0.f;
    #pragma unroll
    for (int nd = 0; nd < 4; nd++) accO[mf][nd] = f32x4{0.f, 0.f, 0.f, 0.f};
  }

  for (int jt = 0; jt <= it; jt++) {
    __syncthreads();   // prior K/V fully consumed
    for (int s = tid; s < 1024; s += 256) {
      const int l = s & 63, g = s >> 6;
      const int row = (g >> 1) * 16 + (l & 15);
      const int c8  = (g & 1) * 4 + (l >> 4);
      GLD_LDS16(Kb + (size_t)(jt * 128 + row) * 4096 + c8 * 8, &sK[s * 8]);
    }
    for (int s = tid; s < 1024; s += 256) {
      const int jc = s >> 6, d = s & 63;
      GLD_LDS16(Vb + ((size_t)(jt * 16 + jc)) * 512 + d * 8, &sV[s * 8]);
    }
    __syncthreads();

    // ---- S^T = K @ Q^T: accST[mf][nf] rows j = nf*16+fg*4+r, cols i ----
    f32x4 accST[2][8];
    #pragma unroll
    for (int mf = 0; mf < 2; mf++)
      #pragma unroll
      for (int nf = 0; nf < 8; nf++) accST[mf][nf] = f32x4{0.f, 0.f, 0.f, 0.f};
    #pragma unroll
    for (int kk = 0; kk < 2; kk++) {
      #pragma unroll
      for (int nf = 0; nf < 8; nf++) {
        const bf16x8 aK = *(const bf16x8*)&sK[((((nf << 1) | kk) << 6) | lane) * 8];
        accST[0][nf] = __builtin_amdgcn_mfma_f32_16x16x32_bf16(aK, bQ[0][kk], accST[0][nf], 0, 0, 0);
        accST[1][nf] = __builtin_amdgcn_mfma_f32_16x16x32_bf16(aK, bQ[1][kk], accST[1][nf], 0, 0, 0);
      }
    }

    // ---- online softmax over j (per lane: i = fr, 32 j's; reduce over fg) ----
    const bool diag = (jt == it);
    bf16x4 pf[2][8];
    #pragma unroll
    for (int mf = 0; mf < 2; mf++) {
      const int iloc = w * 32 + mf * 16 + fr;
      float sv[8][4];
      float rmax = -3.0e38f;
      #pragma unroll
      for (int nf = 0; nf < 8; nf++) {
        #pragma unroll
        for (int r = 0; r < 4; r++) {
          float s = accST[mf][nf][r] * 0.125f;
          if (diag && (nf * 16 + fg * 4 + r) > iloc) s = -3.0e38f;
          sv[nf][r] = s;
          rmax = fmaxf(rmax, s);
        }
      }
      rmax = fmaxf(rmax, __shfl_xor(rmax, 16, 64));
      rmax = fmaxf(rmax, __shfl_xor(rmax, 32, 64));
      const float mn = fmaxf(mrow[mf], rmax);
      const float al = __expf(mrow[mf] - mn);
      mrow[mf] = mn;
      float ps = 0.f;
      #pragma unroll
      for (int nf = 0; nf < 8; nf++) {
        #pragma unroll
        for (int r = 0; r < 4; r++) {
          const float pv = __expf(sv[nf][r] - mn);
          ps += pv;
          pf[mf][nf][r] = (short)f2bf(pv);
        }
      }
      ps += __shfl_xor(ps, 16, 64);
      ps += __shfl_xor(ps, 32, 64);
      lrow[mf] = lrow[mf] * al + ps;
      // rescale accO (rows i = fg*4 + r): fetch alpha from lane fg*4+r
      #pragma unroll
      for (int r = 0; r < 4; r++) {
        const float alr = __shfl(al, fg * 4 + r, 64);
        #pragma unroll
        for (int nd = 0; nd < 4; nd++) accO[mf][nd][r] *= alr;
      }
    }

    // ---- O += P @ V (zero-padded k-slots, exact) ----
    #pragma unroll
    for (int kc = 0; kc < 8; kc++) {
      bf16x8 bV[4];
      #pragma unroll
      for (int nd = 0; nd < 4; nd++) {
        const bf16x4 vv = *(const bf16x4*)&sV[
            (((kc * 2 + (fg >> 1)) * 64 + nd * 16 + fr) * 8) + (fg & 1) * 4];
        bV[nd] = bf16x8{vv[0], vv[1], vv[2], vv[3], 0, 0, 0, 0};
      }
      #pragma unroll
      for (int mf = 0; mf < 2; mf++) {
        const bf16x4 pp = pf[mf][kc];
        const bf16x8 pA = bf16x8{pp[0], pp[1], pp[2], pp[3], 0, 0, 0, 0};
        #pragma unroll
        for (int nd = 0; nd < 4; nd++)
          accO[mf][nd] = __builtin_amdgcn_mfma_f32_16x16x32_bf16(pA, bV[nd], accO[mf][nd], 0, 0, 0);
      }
    }
  }

  // ---- epilogue: out1 row i = w*32+mf*16+fg*4+r, col d = nd*16+fr ----
  u16* op = out1 + ((size_t)(b * T_) + it * 128) * E_ + h * 64;
  #pragma unroll
  for (int mf = 0; mf < 2; mf++) {
    const float li = 1.0f / lrow[mf];
    #pragma unroll
    for (int r = 0; r < 4; r++) {
      const float linv = __shfl(li, fg * 4 + r, 64);
      const int row = w * 32 + mf * 16 + fg * 4 + r;
      #pragma unroll
      for (int nd = 0; nd < 4; nd++)
        op[(size_t)row * E_ + nd * 16 + fr] = f2bf(accO[mf][nd][r] * linv);
    }
  }
}

// ---------------------------------------------------------------------------
// Reductions (256-thread blocks, 4 waves)
// ---------------------------------------------------------------------------
__device__ __forceinline__ float block_max256(float v, float* red) {
  #pragma unroll
  for (int m = 32; m > 0; m >>= 1) v = fmaxf(v, __shfl_xor(v, m, 64));
  if ((threadIdx.x & 63) == 0) red[threadIdx.x >> 6] = v;
  __syncthreads();
  const float r = fmaxf(fmaxf(red[0], red[1]), fmaxf(red[2], red[3]));
  __syncthreads();
  return r;
}
__device__ __forceinline__ float block_sum256(float v, float* red) {
  #pragma unroll
  for (int m = 32; m > 0; m >>= 1) v += __shfl_xor(v, m, 64);
  if ((threadIdx.x & 63) == 0) red[threadIdx.x >> 6] = v;
  __syncthreads();
  const float r = (red[0] + red[1]) + (red[2] + red[3]);
  __syncthreads();
  return r;
}

// ---------------------------------------------------------------------------
// Casts
// ---------------------------------------------------------------------------
__global__ __launch_bounds__(256) void cast_bf16(const float* __restrict__ in, u16* __restrict__ out) {
  const size_t i = ((size_t)blockIdx.x * 256 + threadIdx.x) * 4;
  const float4 v = *(const float4*)(in + i);
  ushort4 o;
  o.x = f2bf(v.x); o.y = f2bf(v.y); o.z = f2bf(v.z); o.w = f2bf(v.w);
  *(ushort4*)(out + i) = o;
}
__global__ __launch_bounds__(256) void cast_split(const float* __restrict__ in,
                                                  u16* __restrict__ hi, u16* __restrict__ lo) {
  const size_t i = ((size_t)blockIdx.x * 256 + threadIdx.x) * 4;
  const float4 v = *(const float4*)(in + i);
  ushort4 oh, ol;
  oh.x = f2bf(v.x); ol.x = f2bf(v.x - bf2f(oh.x));
  oh.y = f2bf(v.y); ol.y = f2bf(v.y - bf2f(oh.y));
  oh.z = f2bf(v.z); ol.z = f2bf(v.z - bf2f(oh.z));
  oh.w = f2bf(v.w); ol.w = f2bf(v.w - bf2f(oh.w));
  *(ushort4*)(hi + i) = oh;
  *(ushort4*)(lo + i) = ol;
}

// ---------------------------------------------------------------------------
// sc[b,t] = ||echo[b,t,:]||^2 / 32   (echo_back GEMM eliminated algebraically)
// ---------------------------------------------------------------------------
__global__ __launch_bounds__(256) void sc_kernel(const float* __restrict__ echo, float* __restrict__ sc) {
  const int row = blockIdx.x;
  const float4 v = ((const float4*)(echo + (size_t)row * E_))[threadIdx.x];
  float ss = v.x * v.x + v.y * v.y + v.z * v.z + v.w * v.w;
  __shared__ float red[4];
  ss = block_sum256(ss, red);
  if (threadIdx.x == 0) sc[row] = ss * (1.0f / 32.0f);
}

// ---------------------------------------------------------------------------
// transpose_wr: wr (H,E,T) f32 -> wrT (H,T,E) bf16; grid (H, T/32, E/32)
// ---------------------------------------------------------------------------
__global__ __launch_bounds__(256) void transpose_wr(const float* __restrict__ wr, u16* __restrict__ wrT) {
  const int h = blockIdx.x;
  const int t0 = blockIdx.y * 32, e0 = blockIdx.z * 32;
  __shared__ float tile[32][33];
  const int c = threadIdx.x & 31, r0 = threadIdx.x >> 5;
  #pragma unroll
  for (int rr = 0; rr < 32; rr += 8) {
    const int e = e0 + r0 + rr;
    tile[r0 + rr][c] = wr[((size_t)h * E_ + e) * T_ + t0 + c];   // coalesced in t
  }
  __syncthreads();
  #pragma unroll
  for (int rr = 0; rr < 32; rr += 8) {
    const int t = t0 + r0 + rr;
    wrT[((size_t)h * T_ + t) * E_ + e0 + c] = f2bf(tile[c][r0 + rr]);  // coalesced in e
  }
}

// ---------------------------------------------------------------------------
// s2_fast: s2[b,h,t] = dot(xb[b,t,:], wrT[h,t,:]) / 8.
// ---------------------------------------------------------------------------
__global__ __launch_bounds__(256) void s2_fast(
    const u16* __restrict__ xb, const u16* __restrict__ wrT, float* __restrict__ s2) {
  const int t = blockIdx.x, b = blockIdx.y;
  const int lane = threadIdx.x & 63;
  const int wv = threadIdx.x >> 6;
  const u16* xr = xb + ((size_t)b * T_ + t) * E_ + lane * 16;
  const bf16x8 xv0 = *(const bf16x8*)xr;
  const bf16x8 xv1 = *(const bf16x8*)(xr + 8);
  #pragma unroll
  for (int hh = 0; hh < 4; hh++) {
    const int h = wv + hh * 4;
    const u16* wp = wrT + ((size_t)h * T_ + t) * E_ + lane * 16;
    const bf16x8 w0 = *(const bf16x8*)wp;
    const bf16x8 w1 = *(const bf16x8*)(wp + 8);
    float acc = 0.f;
    #pragma unroll
    for (int i2 = 0; i2 < 8; i2++) {
      acc += bf2f((u16)xv0[i2]) * bf2f((u16)w0[i2]);
      acc += bf2f((u16)xv1[i2]) * bf2f((u16)w1[i2]);
    }
    #pragma unroll
    for (int mk = 32; mk > 0; mk >>= 1) acc += __shfl_xor(acc, mk, 64);
    if (lane == 0) s2[((size_t)b * H_ + h) * T_ + t] = acc * 0.125f;
  }
}

// ---------------------------------------------------------------------------
// a3[b,i,j] = softmax_{j<=i}(sc_i*sc_j), written bf16 (zeros above diagonal)
// ---------------------------------------------------------------------------
__global__ __launch_bounds__(256) void a3_softmax(const float* __restrict__ sc, u16* __restrict__ a3) {
  const int i = blockIdx.x;
  const int b = blockIdx.y;
  const float* sr = sc + (size_t)b * T_;
  const float sci = sr[i];
  u16* row = a3 + ((size_t)b * T_ + i) * T_;
  __shared__ float red[4];
  float v[4];
  float m = -3.0e38f;
  #pragma unroll
  for (int k = 0; k < 4; k++) {
    const int j = threadIdx.x + k * 256;
    const float xv = (j <= i) ? sci * sr[j] : -3.0e38f;
    v[k] = xv;
    m = fmaxf(m, xv);
  }
  m = block_max256(m, red);
  float s = 0.f;
  #pragma unroll
  for (int k = 0; k < 4; k++) {
    const int j = threadIdx.x + k * 256;
    const float p = (j <= i) ? __expf(v[k] - m) : 0.f;
    v[k] = p;
    s += p;
  }
  s = block_sum256(s, red);
  const float inv = 1.0f / s;
  #pragma unroll
  for (int k = 0; k < 4; k++) {
    const int j = threadIdx.x + k * 256;
    row[j] = f2bf(v[k] * inv);
  }
}

// ---------------------------------------------------------------------------
// Branch 2: broadcast-key softmax => prefix scan, parallelized (round-1 win).
// rv is a strided view (row stride ldrv) into qkvr.
// ---------------------------------------------------------------------------
__global__ __launch_bounds__(1024) void branch2_scan(
    const float* __restrict__ s2, const u16* __restrict__ rv, int ldrv,
    u16* __restrict__ out2) {
  const int h = blockIdx.x, b = blockIdx.y;
  const int tid = threadIdx.x;
  const int lane = tid & 63;   // d
  const int wv = tid >> 6;     // j-chunk index, 0..15

  const float* srow = s2 + ((size_t)b * H_ + h) * T_;

  __shared__ float wbuf[T_];
  __shared__ float numtot[16][64];
  __shared__ float dentot[16];
  __shared__ float redm[16];

  float m = srow[tid];
  #pragma unroll
  for (int mk = 32; mk > 0; mk >>= 1) m = fmaxf(m, __shfl_xor(m, mk, 64));
  if (lane == 0) redm[wv] = m;
  __syncthreads();
  m = redm[0];
  #pragma unroll
  for (int i2 = 1; i2 < 16; i2++) m = fmaxf(m, redm[i2]);

  wbuf[tid] = __expf(srow[tid] - m);
  __syncthreads();

  const u16* rvp = rv + (size_t)(b * T_) * ldrv + h * D_ + lane;
  const int j0 = wv * 64;
  float num = 0.f, den = 0.f;
  #pragma unroll 8
  for (int j2 = 0; j2 < 64; j2++) {
    const float w = wbuf[j0 + j2];
    den += w;
    num += w * bf2f(rvp[(size_t)(j0 + j2) * ldrv]);
  }
  numtot[wv][lane] = num;
  if (lane == 0) dentot[wv] = den;
  __syncthreads();

  float num_off = 0.f, den_off = 0.f;
  for (int w2 = 0; w2 < wv; w2++) {
    num_off += numtot[w2][lane];
    den_off += dentot[w2];
  }

  u16* op = out2 + (size_t)b * T_ * E_ + h * D_ + lane;
  num = num_off; den = den_off;
  #pragma unroll 8
  for (int j2 = 0; j2 < 64; j2++) {
    const float w = wbuf[j0 + j2];
    num += w * bf2f(rvp[(size_t)(j0 + j2) * ldrv]);
    den += w;
    op[(size_t)(j0 + j2) * E_] = f2bf(num / den);
  }
}

// ---------------------------------------------------------------------------
// transpose_v: qkvr v-view (row stride ldv) -> blocked vT' layout:
// vT'[bh][t8][d][t&7]  (per (b,h): 128 t8-blocks x 64 d x 8)
// ---------------------------------------------------------------------------
__global__ __launch_bounds__(256) void transpose_v(const u16* __restrict__ v, u16* __restrict__ vTb,
                                                   int ldv) {
  const int bh = blockIdx.x;
  const int b = bh >> 4, h = bh & 15;
  const int d0 = blockIdx.y * 32, t0 = blockIdx.z * 32;
  __shared__ u16 tile[32][33];
  const int c = threadIdx.x & 31, r0 = threadIdx.x >> 5;
  #pragma unroll
  for (int rr = 0; rr < 32; rr += 8) {
    const int t = t0 + r0 + rr;
    tile[r0 + rr][c] = v[((size_t)b * T_ + t) * ldv + h * 64 + d0 + c];
  }
  __syncthreads();
  #pragma unroll
  for (int rr = 0; rr < 32; rr += 8) {
    const int d = d0 + r0 + rr;
    const int t = t0 + c;
    vTb[((size_t)(bh * 128 + (t >> 3)) * 64 + d) * 8 + (t & 7)] = tile[c][r0 + rr];
  }
}

__global__ __launch_bounds__(256) void transpose_echo(const float* __restrict__ e, u16* __restrict__ eT) {
  const int b = blockIdx.x;
  const int f0 = blockIdx.y * 32, t0 = blockIdx.z * 32;
  __shared__ float tile[32][33];
  const int c = threadIdx.x & 31, r0 = threadIdx.x >> 5;
  #pragma unroll
  for (int rr = 0; rr < 32; rr += 8) {
    const int t = t0 + r0 + rr;
    tile[r0 + rr][c] = e[((size_t)b * T_ + t) * E_ + f0 + c];
  }
  __syncthreads();
  #pragma unroll
  for (int rr = 0; rr < 32; rr += 8) {
    const int f = f0 + r0 + rr;
    eT[((size_t)b * E_ + f) * T_ + t0 + c] = f2bf(tile[c][r0 + rr]);
  }
}

// ---------------------------------------------------------------------------
// Gated combine
// ---------------------------------------------------------------------------
__global__ __launch_bounds__(256) void combine_gate(
    const u16* __restrict__ o1, const u16* __restrict__ o2, const u16* __restrict__ o3,
    const float* __restrict__ gate, u16* __restrict__ comb) {
  const size_t idx = (size_t)blockIdx.x * 256 + threadIdx.x;
  const int f = (int)(idx & (E_ - 1));
  const int h = f >> 6;
  const float g0 = gate[h * 3 + 0], g1 = gate[h * 3 + 1], g2 = gate[h * 3 + 2];
  const float mx = fmaxf(g0, fmaxf(g1, g2));
  const float e0 = __expf(g0 - mx), e1 = __expf(g1 - mx), e2 = __expf(g2 - mx);
  const float inv = 1.0f / (e0 + e1 + e2);
  const float o = (e0 * bf2f(o1[idx]) + e1 * bf2f(o2[idx]) + e2 * bf2f(o3[idx])) * inv;
  comb[idx] = f2bf(o);
}

// ---------------------------------------------------------------------------
extern "C" void kernel_launch(void* const* d_in, const int* in_sizes, int n_in,
                              void* d_out, int out_size, void* d_ws, size_t ws_size,
                              hipStream_t stream) {
  (void)in_sizes; (void)n_in; (void)out_size; (void)ws_size;
  const float* x    = (const float*)d_in[0];
  const float* wq   = (const float*)d_in[1];
  const float* wk   = (const float*)d_in[2];
  const float* wv   = (const float*)d_in[3];
  const float* wvr  = (const float*)d_in[4];
  const float* wr   = (const float*)d_in[5];
  const float* wj   = (const float*)d_in[6];
  const float* gate = (const float*)d_in[7];
  const float* wo   = (const float*)d_in[8];
  float* out = (float*)d_out;

  char* p = (char*)d_ws;
  auto alloc = [&](size_t bytes) -> char* {
    char* r = p; p += (bytes + 255) & ~(size_t)255; return r;
  };
  const size_t NTE = (size_t)B_ * T_ * E_;   // 4M elements
  const size_t NW  = (size_t)E_ * E_;        // 1M elements

  u16* xb    = (u16*)alloc(NTE * 2);
  u16* xlo   = (u16*)alloc(NTE * 2);
  u16* wcat  = (u16*)alloc(4 * NW * 2);      // [wq; wk; wv; wvr] rows
  u16* wjb   = (u16*)alloc(NW * 2);
  u16* wjlo  = (u16*)alloc(NW * 2);
  u16* wob   = (u16*)alloc(NW * 2);
  u16* qkvr  = (u16*)alloc(NTE * 4 * 2);     // (B*T, 4096): q|k|v|rv
  u16* vT    = (u16*)alloc(NTE * 2);         // blocked (bh, t8, d, 8)
  float* echoF = (float*)alloc(NTE * 4);
  u16* echoT = (u16*)alloc(NTE * 2);
  u16* a3p   = (u16*)alloc(NTE * 2);
  float* sc  = (float*)alloc((size_t)B_ * T_ * 4);
  float* s2  = (float*)alloc((size_t)B_ * H_ * T_ * 4);
  u16* wrT   = (u16*)alloc((size_t)H_ * T_ * E_ * 2);
  u16* out1b = (u16*)alloc(NTE * 2);
  u16* out2b = (u16*)alloc(NTE * 2);
  u16* out3b = (u16*)alloc(NTE * 2);
  u16* comb  = (u16*)alloc(NTE * 2);

  // ---- casts ----
  cast_split<<<dim3((unsigned)(NTE / 1024)), 256, 0, stream>>>(x, xb, xlo);
  cast_bf16 <<<dim3((unsigned)(NW / 1024)), 256, 0, stream>>>(wq, wcat);
  cast_bf16 <<<dim3((unsigned)(NW / 1024)), 256, 0, stream>>>(wk, wcat + NW);
  cast_bf16 <<<dim3((unsigned)(NW / 1024)), 256, 0, stream>>>(wv, wcat + 2 * NW);
  cast_bf16 <<<dim3((unsigned)(NW / 1024)), 256, 0, stream>>>(wvr, wcat + 3 * NW);
  cast_bf16 <<<dim3((unsigned)(NW / 1024)), 256, 0, stream>>>(wo, wob);
  cast_split<<<dim3((unsigned)(NW / 1024)), 256, 0, stream>>>(wj, wjb, wjlo);

  // ---- fused q|k|v|rv projection: (B*T,1024) @ (4096,1024)^T -> (B*T,4096) ----
  gemm_bt<2,2,4,4,false,true><<<dim3(32, 32, 1), 256, 0, stream>>>(
      xb, nullptr, wcat, nullptr, qkvr, 4096, E_, E_, E_, 4096, 0L, 0L, 0L, 1.f);

  // ---- echo in split-bf16, 128x64 tiles for 2 blocks/CU ----
  gemm_bt<2,2,4,2,true,false><<<dim3(16, 32, 1), 256, 0, stream>>>(
      xb, xlo, wjb, wjlo, echoF, E_, E_, E_, E_, E_, 0L, 0L, 0L, 1.f);

  // ---- side computations ----
  transpose_v<<<dim3(B_ * H_, D_ / 32, T_ / 32), 256, 0, stream>>>(qkvr + 2048, vT, 4096);
  sc_kernel<<<dim3(B_ * T_), 256, 0, stream>>>(echoF, sc);
  transpose_echo<<<dim3(B_, E_ / 32, T_ / 32), 256, 0, stream>>>(echoF, echoT);
  transpose_wr<<<dim3(H_, T_ / 32, E_ / 32), 256, 0, stream>>>(wr, wrT);
  s2_fast<<<dim3(T_, B_), 256, 0, stream>>>(xb, wrT, s2);

  // ---- branch 2 ----
  branch2_scan<<<dim3(H_, B_), 1024, 0, stream>>>(s2, qkvr + 3072, 4096, out2b);

  // ---- branch 3 ----
  a3_softmax<<<dim3(T_, B_), 256, 0, stream>>>(sc, a3p);
  gemm_bt<2,2,4,4,false,true><<<dim3(E_ / 128, T_ / 128, B_), 256, 0, stream>>>(
      a3p, nullptr, echoT, nullptr, out3b, E_, T_, T_, T_, E_,
      (long)T_ * T_, (long)E_ * T_, (long)T_ * E_, 1.f);

  // ---- branch 1: flash-fused, register-resident ----
  flash1<<<dim3(T_ / 128, H_, B_), 256, 0, stream>>>(qkvr, vT, out1b);

  // ---- combine + output projection ----
  combine_gate<<<dim3((unsigned)(NTE / 256)), 256, 0, stream>>>(out1b, out2b, out3b, gate, comb);
  gemm_bt<2,2,4,4,false,false><<<dim3(E_ / 128, (B_ * T_) / 128, 1), 256, 0, stream>>>(
      comb, nullptr, wob, nullptr, out, E_, E_, E_, E_, E_, 0L, 0L, 0L, 1.f);
}

// Round 7
// 395.995 us; speedup vs baseline: 2.0643x; 1.0763x over previous
//
#include <hip/hip_runtime.h>
#include <cstdint>
#include <cstddef>

typedef unsigned short u16;
typedef short bf16x8 __attribute__((ext_vector_type(8)));
typedef short bf16x4 __attribute__((ext_vector_type(4)));
typedef float f32x4 __attribute__((ext_vector_type(4)));

constexpr int B_ = 4, T_ = 1024, E_ = 1024, H_ = 16, D_ = 64;

__device__ __forceinline__ float bf2f(u16 u) {
  union { unsigned u; float f; } v; v.u = ((unsigned)u) << 16; return v.f;
}
__device__ __forceinline__ u16 f2bf(float f) {
  union { float f; unsigned u; } v; v.f = f;
  return (u16)((v.u + 0x7fffu + ((v.u >> 16) & 1u)) >> 16);
}

#define GLD_LDS16(gp, lp)                                                      \
  __builtin_amdgcn_global_load_lds(                                            \
      (const __attribute__((address_space(1))) void*)(gp),                     \
      (__attribute__((address_space(3))) void*)(lp), 16, 0, 0)

// ---------------------------------------------------------------------------
// Tiled bf16 MFMA GEMM, C = alpha * A @ B^T.  (m97 structure; see round 0)
// ---------------------------------------------------------------------------
template<int WM, int WN, int MT, int NT, bool CBF16>
__global__ __launch_bounds__(WM * WN * 64) void gemm_bt(
    const u16* __restrict__ A, const u16* __restrict__ Bm,
    void* __restrict__ Cv, int N, int K,
    int lda, int ldb, int ldc,
    long batchA, long batchB, long batchC, float alpha)
{
  constexpr int TM = WM * MT * 16;
  constexpr int TN = WN * NT * 16;
  constexpr int THREADS = WM * WN * 64;
  constexpr int ASZ = TM * 32, BSZ = TN * 32;

  __shared__ u16 smem[ASZ + BSZ];
  u16* sA = smem;
  u16* sB = smem + ASZ;

  const int z = blockIdx.z;
  const u16* Ab = A + (size_t)z * batchA;
  const u16* Bb = Bm + (size_t)z * batchB;
  const int m0 = blockIdx.y * TM;
  const int n0 = blockIdx.x * TN;
  const int tid = threadIdx.x;
  const int lane = tid & 63;
  const int wave = tid >> 6;
  const int wm = wave % WM;
  const int wn = wave / WM;
  const int fr = lane & 15;
  const int fg = lane >> 4;

  f32x4 acc[MT][NT];
  const f32x4 zero = {0.f, 0.f, 0.f, 0.f};
  #pragma unroll
  for (int i = 0; i < MT; i++)
    #pragma unroll
    for (int j = 0; j < NT; j++) acc[i][j] = zero;

  for (int k0 = 0; k0 < K; k0 += 32) {
    __syncthreads();
    for (int s = tid; s < TM * 4; s += THREADS) {
      const int row = s >> 2, ch = s & 3;
      GLD_LDS16(Ab + (size_t)(m0 + row) * lda + k0 + ch * 8, &sA[s * 8]);
    }
    for (int s = tid; s < TN * 4; s += THREADS) {
      const int row = s >> 2, ch = s & 3;
      int rr = n0 + row; if (rr > N - 1) rr = N - 1;
      GLD_LDS16(Bb + (size_t)rr * ldb + k0 + ch * 8, &sB[s * 8]);
    }
    __syncthreads();

    bf16x8 av[MT], bv[NT];
    #pragma unroll
    for (int mt = 0; mt < MT; mt++)
      av[mt] = *(const bf16x8*)&sA[((wm * MT + mt) * 16 + fr) * 32 + fg * 8];
    #pragma unroll
    for (int nt = 0; nt < NT; nt++)
      bv[nt] = *(const bf16x8*)&sB[((wn * NT + nt) * 16 + fr) * 32 + fg * 8];
    #pragma unroll
    for (int mt = 0; mt < MT; mt++)
      #pragma unroll
      for (int nt = 0; nt < NT; nt++)
        acc[mt][nt] = __builtin_amdgcn_mfma_f32_16x16x32_bf16(av[mt], bv[nt], acc[mt][nt], 0, 0, 0);
  }

  const int er = (lane >> 4) * 4;
  const int ec = lane & 15;
  #pragma unroll
  for (int mt = 0; mt < MT; mt++) {
    #pragma unroll
    for (int nt = 0; nt < NT; nt++) {
      const int row = m0 + (wm * MT + mt) * 16 + er;
      const int col = n0 + (wn * NT + nt) * 16 + ec;
      if (col < N) {
        #pragma unroll
        for (int r2 = 0; r2 < 4; r2++) {
          const float vv = acc[mt][nt][r2] * alpha;
          const size_t ci = (size_t)z * batchC + (size_t)(row + r2) * ldc + col;
          if constexpr (CBF16) ((u16*)Cv)[ci] = f2bf(vv);
          else                 ((float*)Cv)[ci] = vv;
        }
      }
    }
  }
}

// ---------------------------------------------------------------------------
// gemm_echo: split-bf16 GEMM (fp32-class product) 128x64 tile, fused epilogue:
//   - echoT[b, f, t] bf16 written via LDS tile transpose (coalesced)
//   - sc[b,t] += sum_f echo^2 (lane-reduced atomicAdd; caller memsets sc=0)
// A=xb hi, Alo=xlo, B=wjb, Blo=wjlo, K=E.
// ---------------------------------------------------------------------------
__global__ __launch_bounds__(256) void gemm_echo(
    const u16* __restrict__ A, const u16* __restrict__ Alo,
    const u16* __restrict__ Bm, const u16* __restrict__ Blo,
    u16* __restrict__ echoT, float* __restrict__ sc)
{
  constexpr int TM = 128, TN = 64;
  constexpr int ASZ = TM * 32, BSZ = TN * 32;   // 4096, 2048 u16
  __shared__ u16 smem[2 * (ASZ + BSZ)];         // 24 KB; epilogue reuses 64*132
  u16* sA  = smem;
  u16* sB  = smem + ASZ;
  u16* sAl = smem + ASZ + BSZ;
  u16* sBl = smem + 2 * ASZ + BSZ;

  const int m0 = blockIdx.y * TM;
  const int n0 = blockIdx.x * TN;
  const int tid = threadIdx.x;
  const int lane = tid & 63;
  const int wave = tid >> 6;
  const int wm = wave % 2;
  const int wn = wave / 2;
  const int fr = lane & 15, fg = lane >> 4;

  f32x4 acc[4][2];
  #pragma unroll
  for (int i = 0; i < 4; i++)
    #pragma unroll
    for (int j = 0; j < 2; j++) acc[i][j] = f32x4{0.f, 0.f, 0.f, 0.f};

  for (int k0 = 0; k0 < E_; k0 += 32) {
    __syncthreads();
    for (int s = tid; s < TM * 4; s += 256) {
      const int row = s >> 2, ch = s & 3;
      const size_t go = (size_t)(m0 + row) * E_ + k0 + ch * 8;
      GLD_LDS16(A + go, &sA[s * 8]);
      GLD_LDS16(Alo + go, &sAl[s * 8]);
    }
    for (int s = tid; s < TN * 4; s += 256) {
      const int row = s >> 2, ch = s & 3;
      const size_t go = (size_t)(n0 + row) * E_ + k0 + ch * 8;
      GLD_LDS16(Bm + go, &sB[s * 8]);
      GLD_LDS16(Blo + go, &sBl[s * 8]);
    }
    __syncthreads();

    bf16x8 av[4], bv[2], al[4], bl[2];
    #pragma unroll
    for (int mt = 0; mt < 4; mt++) {
      av[mt] = *(const bf16x8*)&sA[((wm * 4 + mt) * 16 + fr) * 32 + fg * 8];
      al[mt] = *(const bf16x8*)&sAl[((wm * 4 + mt) * 16 + fr) * 32 + fg * 8];
    }
    #pragma unroll
    for (int nt = 0; nt < 2; nt++) {
      bv[nt] = *(const bf16x8*)&sB[((wn * 2 + nt) * 16 + fr) * 32 + fg * 8];
      bl[nt] = *(const bf16x8*)&sBl[((wn * 2 + nt) * 16 + fr) * 32 + fg * 8];
    }
    #pragma unroll
    for (int mt = 0; mt < 4; mt++)
      #pragma unroll
      for (int nt = 0; nt < 2; nt++) {
        acc[mt][nt] = __builtin_amdgcn_mfma_f32_16x16x32_bf16(av[mt], bv[nt], acc[mt][nt], 0, 0, 0);
        acc[mt][nt] = __builtin_amdgcn_mfma_f32_16x16x32_bf16(al[mt], bv[nt], acc[mt][nt], 0, 0, 0);
        acc[mt][nt] = __builtin_amdgcn_mfma_f32_16x16x32_bf16(av[mt], bl[nt], acc[mt][nt], 0, 0, 0);
      }
  }

  // ---- fused epilogue ----
  __syncthreads();                 // all LDS frag reads done; reuse smem
  const int b   = m0 >> 10;
  const int t0l = m0 & 1023;
  const int ec  = lane & 15;
  u16* lt = smem;                  // [f][t] tile, pad 132

  #pragma unroll
  for (int mt = 0; mt < 4; mt++) {
    float sq[4] = {0.f, 0.f, 0.f, 0.f};
    #pragma unroll
    for (int nt = 0; nt < 2; nt++) {
      const int cl = (wn * 2 + nt) * 16 + ec;
      #pragma unroll
      for (int r2 = 0; r2 < 4; r2++) {
        const float vv = acc[mt][nt][r2];
        sq[r2] += vv * vv;
        lt[cl * 132 + (wm * 4 + mt) * 16 + fg * 4 + r2] = f2bf(vv);
      }
    }
    #pragma unroll
    for (int m2 = 1; m2 < 16; m2 <<= 1) {
      sq[0] += __shfl_xor(sq[0], m2, 64);
      sq[1] += __shfl_xor(sq[1], m2, 64);
      sq[2] += __shfl_xor(sq[2], m2, 64);
      sq[3] += __shfl_xor(sq[3], m2, 64);
    }
    if (ec == 0) {
      #pragma unroll
      for (int r2 = 0; r2 < 4; r2++)
        atomicAdd(&sc[(size_t)b * T_ + t0l + (wm * 4 + mt) * 16 + fg * 4 + r2], sq[r2]);
    }
  }
  __syncthreads();
  for (int s = tid; s < 64 * 128; s += 256) {
    const int f = s >> 7, t = s & 127;
    echoT[((size_t)b * E_ + n0 + f) * T_ + t0l + t] = lt[f * 132 + t];
  }
}

// ---------------------------------------------------------------------------
// Flash-fused branch 1, register-resident (round-6 win).
// ---------------------------------------------------------------------------
__global__ __launch_bounds__(256, 2) void flash1(
    const u16* __restrict__ qkvr, const u16* __restrict__ vTb, u16* __restrict__ out1) {
  const int it = blockIdx.x, h = blockIdx.y, b = blockIdx.z;
  const int tid = threadIdx.x, lane = tid & 63, w = tid >> 6;
  const int fr = lane & 15, fg = lane >> 4;

  __shared__ u16 sQ[8192];
  __shared__ u16 sK[8192];
  __shared__ u16 sV[8192];

  const u16* Qb = qkvr + ((size_t)(b * T_) + it * 128) * 4096 + h * 64;
  const u16* Kb = qkvr + (size_t)(b * T_) * 4096 + 1024 + h * 64;
  const u16* Vb = vTb + (size_t)(b * H_ + h) * (D_ * T_);

  for (int s = tid; s < 1024; s += 256) {
    const int l = s & 63, g = s >> 6;
    const int row = (g >> 1) * 16 + (l & 15);
    const int c8  = (g & 1) * 4 + (l >> 4);
    GLD_LDS16(Qb + (size_t)row * 4096 + c8 * 8, &sQ[s * 8]);
  }
  __syncthreads();

  bf16x8 bQ[2][2];
  #pragma unroll
  for (int mf = 0; mf < 2; mf++)
    #pragma unroll
    for (int kk = 0; kk < 2; kk++)
      bQ[mf][kk] = *(const bf16x8*)&sQ[((((w * 2 + mf) * 2 + kk) << 6) | lane) * 8];

  f32x4 accO[2][4];
  float mrow[2], lrow[2];
  #pragma unroll
  for (int mf = 0; mf < 2; mf++) {
    mrow[mf] = -3.0e38f; lrow[mf] = 0.f;
    #pragma unroll
    for (int nd = 0; nd < 4; nd++) accO[mf][nd] = f32x4{0.f, 0.f, 0.f, 0.f};
  }

  for (int jt = 0; jt <= it; jt++) {
    __syncthreads();
    for (int s = tid; s < 1024; s += 256) {
      const int l = s & 63, g = s >> 6;
      const int row = (g >> 1) * 16 + (l & 15);
      const int c8  = (g & 1) * 4 + (l >> 4);
      GLD_LDS16(Kb + (size_t)(jt * 128 + row) * 4096 + c8 * 8, &sK[s * 8]);
    }
    for (int s = tid; s < 1024; s += 256) {
      const int jc = s >> 6, d = s & 63;
      GLD_LDS16(Vb + ((size_t)(jt * 16 + jc)) * 512 + d * 8, &sV[s * 8]);
    }
    __syncthreads();

    f32x4 accST[2][8];
    #pragma unroll
    for (int mf = 0; mf < 2; mf++)
      #pragma unroll
      for (int nf = 0; nf < 8; nf++) accST[mf][nf] = f32x4{0.f, 0.f, 0.f, 0.f};
    #pragma unroll
    for (int kk = 0; kk < 2; kk++) {
      #pragma unroll
      for (int nf = 0; nf < 8; nf++) {
        const bf16x8 aK = *(const bf16x8*)&sK[((((nf << 1) | kk) << 6) | lane) * 8];
        accST[0][nf] = __builtin_amdgcn_mfma_f32_16x16x32_bf16(aK, bQ[0][kk], accST[0][nf], 0, 0, 0);
        accST[1][nf] = __builtin_amdgcn_mfma_f32_16x16x32_bf16(aK, bQ[1][kk], accST[1][nf], 0, 0, 0);
      }
    }

    const bool diag = (jt == it);
    bf16x4 pf[2][8];
    #pragma unroll
    for (int mf = 0; mf < 2; mf++) {
      const int iloc = w * 32 + mf * 16 + fr;
      float sv[8][4];
      float rmax = -3.0e38f;
      #pragma unroll
      for (int nf = 0; nf < 8; nf++)
        #pragma unroll
        for (int r = 0; r < 4; r++) {
          float s = accST[mf][nf][r] * 0.125f;
          if (diag && (nf * 16 + fg * 4 + r) > iloc) s = -3.0e38f;
          sv[nf][r] = s;
          rmax = fmaxf(rmax, s);
        }
      rmax = fmaxf(rmax, __shfl_xor(rmax, 16, 64));
      rmax = fmaxf(rmax, __shfl_xor(rmax, 32, 64));
      const float mn = fmaxf(mrow[mf], rmax);
      const float al = __expf(mrow[mf] - mn);
      mrow[mf] = mn;
      float ps = 0.f;
      #pragma unroll
      for (int nf = 0; nf < 8; nf++)
        #pragma unroll
        for (int r = 0; r < 4; r++) {
          const float pv = __expf(sv[nf][r] - mn);
          ps += pv;
          pf[mf][nf][r] = (short)f2bf(pv);
        }
      ps += __shfl_xor(ps, 16, 64);
      ps += __shfl_xor(ps, 32, 64);
      lrow[mf] = lrow[mf] * al + ps;
      #pragma unroll
      for (int r = 0; r < 4; r++) {
        const float alr = __shfl(al, fg * 4 + r, 64);
        #pragma unroll
        for (int nd = 0; nd < 4; nd++) accO[mf][nd][r] *= alr;
      }
    }

    #pragma unroll
    for (int kc = 0; kc < 8; kc++) {
      bf16x8 bV[4];
      #pragma unroll
      for (int nd = 0; nd < 4; nd++) {
        const bf16x4 vv = *(const bf16x4*)&sV[
            (((kc * 2 + (fg >> 1)) * 64 + nd * 16 + fr) * 8) + (fg & 1) * 4];
        bV[nd] = bf16x8{vv[0], vv[1], vv[2], vv[3], 0, 0, 0, 0};
      }
      #pragma unroll
      for (int mf = 0; mf < 2; mf++) {
        const bf16x4 pp = pf[mf][kc];
        const bf16x8 pA = bf16x8{pp[0], pp[1], pp[2], pp[3], 0, 0, 0, 0};
        #pragma unroll
        for (int nd = 0; nd < 4; nd++)
          accO[mf][nd] = __builtin_amdgcn_mfma_f32_16x16x32_bf16(pA, bV[nd], accO[mf][nd], 0, 0, 0);
      }
    }
  }

  u16* op = out1 + ((size_t)(b * T_) + it * 128) * E_ + h * 64;
  #pragma unroll
  for (int mf = 0; mf < 2; mf++) {
    const float li = 1.0f / lrow[mf];
    #pragma unroll
    for (int r = 0; r < 4; r++) {
      const float linv = __shfl(li, fg * 4 + r, 64);
      const int row = w * 32 + mf * 16 + fg * 4 + r;
      #pragma unroll
      for (int nd = 0; nd < 4; nd++)
        op[(size_t)row * E_ + nd * 16 + fr] = f2bf(accO[mf][nd][r] * linv);
    }
  }
}

// ---------------------------------------------------------------------------
// Reductions
// ---------------------------------------------------------------------------
__device__ __forceinline__ float block_max256(float v, float* red) {
  #pragma unroll
  for (int m = 32; m > 0; m >>= 1) v = fmaxf(v, __shfl_xor(v, m, 64));
  if ((threadIdx.x & 63) == 0) red[threadIdx.x >> 6] = v;
  __syncthreads();
  const float r = fmaxf(fmaxf(red[0], red[1]), fmaxf(red[2], red[3]));
  __syncthreads();
  return r;
}
__device__ __forceinline__ float block_sum256(float v, float* red) {
  #pragma unroll
  for (int m = 32; m > 0; m >>= 1) v += __shfl_xor(v, m, 64);
  if ((threadIdx.x & 63) == 0) red[threadIdx.x >> 6] = v;
  __syncthreads();
  const float r = (red[0] + red[1]) + (red[2] + red[3]);
  __syncthreads();
  return r;
}

// ---------------------------------------------------------------------------
// cast_all: x split (4096 blocks) | wq/wk/wv/wvr -> wcat (4096) |
//           wo -> wob (1024) | wj split (1024).  One dispatch, 10240 blocks.
// ---------------------------------------------------------------------------
__global__ __launch_bounds__(256) void cast_all(
    const float* __restrict__ x, const float* __restrict__ wq,
    const float* __restrict__ wk, const float* __restrict__ wv,
    const float* __restrict__ wvr, const float* __restrict__ wo,
    const float* __restrict__ wj,
    u16* __restrict__ xb, u16* __restrict__ xlo, u16* __restrict__ wcat,
    u16* __restrict__ wob, u16* __restrict__ wjb, u16* __restrict__ wjlo) {
  const int bid = blockIdx.x;
  if (bid < 4096) {
    const size_t i = ((size_t)bid * 256 + threadIdx.x) * 4;
    const float4 v = *(const float4*)(x + i);
    ushort4 oh, ol;
    oh.x = f2bf(v.x); ol.x = f2bf(v.x - bf2f(oh.x));
    oh.y = f2bf(v.y); ol.y = f2bf(v.y - bf2f(oh.y));
    oh.z = f2bf(v.z); ol.z = f2bf(v.z - bf2f(oh.z));
    oh.w = f2bf(v.w); ol.w = f2bf(v.w - bf2f(oh.w));
    *(ushort4*)(xb + i) = oh;
    *(ushort4*)(xlo + i) = ol;
  } else if (bid < 8192) {
    const int r = (bid - 4096) >> 10;
    const float* src = (r == 0) ? wq : (r == 1) ? wk : (r == 2) ? wv : wvr;
    const size_t i = ((size_t)((bid - 4096) & 1023) * 256 + threadIdx.x) * 4;
    const float4 v = *(const float4*)(src + i);
    ushort4 o;
    o.x = f2bf(v.x); o.y = f2bf(v.y); o.z = f2bf(v.z); o.w = f2bf(v.w);
    *(ushort4*)(wcat + (size_t)r * (1 << 20) + i) = o;
  } else if (bid < 9216) {
    const size_t i = ((size_t)(bid - 8192) * 256 + threadIdx.x) * 4;
    const float4 v = *(const float4*)(wo + i);
    ushort4 o;
    o.x = f2bf(v.x); o.y = f2bf(v.y); o.z = f2bf(v.z); o.w = f2bf(v.w);
    *(ushort4*)(wob + i) = o;
  } else {
    const size_t i = ((size_t)(bid - 9216) * 256 + threadIdx.x) * 4;
    const float4 v = *(const float4*)(wj + i);
    ushort4 oh, ol;
    oh.x = f2bf(v.x); ol.x = f2bf(v.x - bf2f(oh.x));
    oh.y = f2bf(v.y); ol.y = f2bf(v.y - bf2f(oh.y));
    oh.z = f2bf(v.z); ol.z = f2bf(v.z - bf2f(oh.z));
    oh.w = f2bf(v.w); ol.w = f2bf(v.w - bf2f(oh.w));
    *(ushort4*)(wjb + i) = oh;
    *(ushort4*)(wjlo + i) = ol;
  }
}

// ---------------------------------------------------------------------------
// s2_direct: s2[b,h,t] = dot(x[b,t,:], wr[h,:,t]) / 8 without materializing
// wrT. Grid (T/32, H). Thread (tt, eg): t = t0+tt, e-range eg*16 within each
// 128-chunk. wr reads coalesced in t; x bf16x8 reads served by L1/L2.
// ---------------------------------------------------------------------------
__global__ __launch_bounds__(256) void s2_direct(
    const u16* __restrict__ xb, const float* __restrict__ wr, float* __restrict__ s2) {
  const int t0 = blockIdx.x * 32, h = blockIdx.y;
  const int tt = threadIdx.x & 31, eg = threadIdx.x >> 5;
  float acc[4] = {0.f, 0.f, 0.f, 0.f};
  const float* wp = wr + (size_t)h * E_ * T_ + t0 + tt;
  for (int ec = 0; ec < 8; ec++) {
    const int e0 = ec * 128 + eg * 16;
    bf16x8 xv[4][2];
    #pragma unroll
    for (int b = 0; b < 4; b++) {
      const u16* xp = xb + ((size_t)(b * T_) + t0 + tt) * E_ + e0;
      xv[b][0] = *(const bf16x8*)xp;
      xv[b][1] = *(const bf16x8*)(xp + 8);
    }
    #pragma unroll
    for (int e2 = 0; e2 < 16; e2++) {
      const float w = wp[(size_t)(e0 + e2) * T_];
      #pragma unroll
      for (int b = 0; b < 4; b++)
        acc[b] += bf2f((u16)xv[b][e2 >> 3][e2 & 7]) * w;
    }
  }
  __shared__ float red[8][4][33];
  #pragma unroll
  for (int b = 0; b < 4; b++) red[eg][b][tt] = acc[b];
  __syncthreads();
  if (threadIdx.x < 128) {
    const int b = threadIdx.x >> 5, t = threadIdx.x & 31;
    float s = 0.f;
    #pragma unroll
    for (int g = 0; g < 8; g++) s += red[g][b][t];
    s2[((size_t)b * H_ + h) * T_ + t0 + t] = s * 0.125f;
  }
}

// ---------------------------------------------------------------------------
// a3[b,i,j] = softmax_{j<=i}(sc_i*sc_j/1024)  (sc holds raw sum of squares)
// ---------------------------------------------------------------------------
__global__ __launch_bounds__(256) void a3_softmax(const float* __restrict__ sc, u16* __restrict__ a3) {
  const int i = blockIdx.x;
  const int b = blockIdx.y;
  const float* sr = sc + (size_t)b * T_;
  const float sci = sr[i] * 0.03125f;
  u16* row = a3 + ((size_t)b * T_ + i) * T_;
  __shared__ float red[4];
  float v[4];
  float m = -3.0e38f;
  #pragma unroll
  for (int k = 0; k < 4; k++) {
    const int j = threadIdx.x + k * 256;
    const float xv = (j <= i) ? sci * (sr[j] * 0.03125f) : -3.0e38f;
    v[k] = xv;
    m = fmaxf(m, xv);
  }
  m = block_max256(m, red);
  float s = 0.f;
  #pragma unroll
  for (int k = 0; k < 4; k++) {
    const int j = threadIdx.x + k * 256;
    const float p = (j <= i) ? __expf(v[k] - m) : 0.f;
    v[k] = p;
    s += p;
  }
  s = block_sum256(s, red);
  const float inv = 1.0f / s;
  #pragma unroll
  for (int k = 0; k < 4; k++) {
    const int j = threadIdx.x + k * 256;
    row[j] = f2bf(v[k] * inv);
  }
}

// ---------------------------------------------------------------------------
// Branch 2: prefix scan (round-1 win). rv strided view into qkvr.
// ---------------------------------------------------------------------------
__global__ __launch_bounds__(1024) void branch2_scan(
    const float* __restrict__ s2, const u16* __restrict__ rv, int ldrv,
    u16* __restrict__ out2) {
  const int h = blockIdx.x, b = blockIdx.y;
  const int tid = threadIdx.x;
  const int lane = tid & 63;
  const int wv = tid >> 6;

  const float* srow = s2 + ((size_t)b * H_ + h) * T_;

  __shared__ float wbuf[T_];
  __shared__ float numtot[16][64];
  __shared__ float dentot[16];
  __shared__ float redm[16];

  float m = srow[tid];
  #pragma unroll
  for (int mk = 32; mk > 0; mk >>= 1) m = fmaxf(m, __shfl_xor(m, mk, 64));
  if (lane == 0) redm[wv] = m;
  __syncthreads();
  m = redm[0];
  #pragma unroll
  for (int i2 = 1; i2 < 16; i2++) m = fmaxf(m, redm[i2]);

  wbuf[tid] = __expf(srow[tid] - m);
  __syncthreads();

  const u16* rvp = rv + (size_t)(b * T_) * ldrv + h * D_ + lane;
  const int j0 = wv * 64;
  float num = 0.f, den = 0.f;
  #pragma unroll 8
  for (int j2 = 0; j2 < 64; j2++) {
    const float w = wbuf[j0 + j2];
    den += w;
    num += w * bf2f(rvp[(size_t)(j0 + j2) * ldrv]);
  }
  numtot[wv][lane] = num;
  if (lane == 0) dentot[wv] = den;
  __syncthreads();

  float num_off = 0.f, den_off = 0.f;
  for (int w2 = 0; w2 < wv; w2++) {
    num_off += numtot[w2][lane];
    den_off += dentot[w2];
  }

  u16* op = out2 + (size_t)b * T_ * E_ + h * D_ + lane;
  num = num_off; den = den_off;
  #pragma unroll 8
  for (int j2 = 0; j2 < 64; j2++) {
    const float w = wbuf[j0 + j2];
    num += w * bf2f(rvp[(size_t)(j0 + j2) * ldrv]);
    den += w;
    op[(size_t)(j0 + j2) * E_] = f2bf(num / den);
  }
}

// ---------------------------------------------------------------------------
// transpose_v: qkvr v-view -> blocked vT' [bh][t8][d][t&7]
// ---------------------------------------------------------------------------
__global__ __launch_bounds__(256) void transpose_v(const u16* __restrict__ v, u16* __restrict__ vTb,
                                                   int ldv) {
  const int bh = blockIdx.x;
  const int b = bh >> 4, h = bh & 15;
  const int d0 = blockIdx.y * 32, t0 = blockIdx.z * 32;
  __shared__ u16 tile[32][33];
  const int c = threadIdx.x & 31, r0 = threadIdx.x >> 5;
  #pragma unroll
  for (int rr = 0; rr < 32; rr += 8) {
    const int t = t0 + rr + r0;
    tile[rr + r0][c] = v[((size_t)b * T_ + t) * ldv + h * 64 + d0 + c];
  }
  __syncthreads();
  #pragma unroll
  for (int rr = 0; rr < 32; rr += 8) {
    const int d = d0 + rr + r0;
    const int t = t0 + c;
    vTb[((size_t)(bh * 128 + (t >> 3)) * 64 + d) * 8 + (t & 7)] = tile[c][rr + r0];
  }
}

// ---------------------------------------------------------------------------
// Gated combine
// ---------------------------------------------------------------------------
__global__ __launch_bounds__(256) void combine_gate(
    const u16* __restrict__ o1, const u16* __restrict__ o2, const u16* __restrict__ o3,
    const float* __restrict__ gate, u16* __restrict__ comb) {
  const size_t idx = (size_t)blockIdx.x * 256 + threadIdx.x;
  const int f = (int)(idx & (E_ - 1));
  const int h = f >> 6;
  const float g0 = gate[h * 3 + 0], g1 = gate[h * 3 + 1], g2 = gate[h * 3 + 2];
  const float mx = fmaxf(g0, fmaxf(g1, g2));
  const float e0 = __expf(g0 - mx), e1 = __expf(g1 - mx), e2 = __expf(g2 - mx);
  const float inv = 1.0f / (e0 + e1 + e2);
  const float o = (e0 * bf2f(o1[idx]) + e1 * bf2f(o2[idx]) + e2 * bf2f(o3[idx])) * inv;
  comb[idx] = f2bf(o);
}

// ---------------------------------------------------------------------------
extern "C" void kernel_launch(void* const* d_in, const int* in_sizes, int n_in,
                              void* d_out, int out_size, void* d_ws, size_t ws_size,
                              hipStream_t stream) {
  (void)in_sizes; (void)n_in; (void)out_size; (void)ws_size;
  const float* x    = (const float*)d_in[0];
  const float* wq   = (const float*)d_in[1];
  const float* wk   = (const float*)d_in[2];
  const float* wv   = (const float*)d_in[3];
  const float* wvr  = (const float*)d_in[4];
  const float* wr   = (const float*)d_in[5];
  const float* wj   = (const float*)d_in[6];
  const float* gate = (const float*)d_in[7];
  const float* wo   = (const float*)d_in[8];
  float* out = (float*)d_out;

  char* p = (char*)d_ws;
  auto alloc = [&](size_t bytes) -> char* {
    char* r = p; p += (bytes + 255) & ~(size_t)255; return r;
  };
  const size_t NTE = (size_t)B_ * T_ * E_;   // 4M elements
  const size_t NW  = (size_t)E_ * E_;        // 1M elements

  u16* xb    = (u16*)alloc(NTE * 2);
  u16* xlo   = (u16*)alloc(NTE * 2);
  u16* wcat  = (u16*)alloc(4 * NW * 2);
  u16* wjb   = (u16*)alloc(NW * 2);
  u16* wjlo  = (u16*)alloc(NW * 2);
  u16* wob   = (u16*)alloc(NW * 2);
  u16* qkvr  = (u16*)alloc(NTE * 4 * 2);     // (B*T, 4096): q|k|v|rv
  u16* vT    = (u16*)alloc(NTE * 2);         // blocked (bh, t8, d, 8)
  u16* echoT = (u16*)alloc(NTE * 2);         // (B, E, T) bf16
  u16* a3p   = (u16*)alloc(NTE * 2);
  float* sc  = (float*)alloc((size_t)B_ * T_ * 4);
  float* s2  = (float*)alloc((size_t)B_ * H_ * T_ * 4);
  u16* out1b = (u16*)alloc(NTE * 2);
  u16* out2b = (u16*)alloc(NTE * 2);
  u16* out3b = (u16*)alloc(NTE * 2);
  u16* comb  = (u16*)alloc(NTE * 2);

  // ---- all casts in one dispatch; sc zeroed for atomic accumulation ----
  cast_all<<<dim3(10240), 256, 0, stream>>>(x, wq, wk, wv, wvr, wo, wj,
                                            xb, xlo, wcat, wob, wjb, wjlo);
  hipMemsetAsync(sc, 0, (size_t)B_ * T_ * 4, stream);

  // ---- fused q|k|v|rv projection ----
  gemm_bt<2,2,4,4,true><<<dim3(32, 32, 1), 256, 0, stream>>>(
      xb, wcat, qkvr, 4096, E_, E_, E_, 4096, 0L, 0L, 0L, 1.f);

  // ---- echo split-GEMM with fused echoT + sc epilogue ----
  gemm_echo<<<dim3(16, 32, 1), 256, 0, stream>>>(xb, xlo, wjb, wjlo, echoT, sc);

  // ---- side computations ----
  transpose_v<<<dim3(B_ * H_, D_ / 32, T_ / 32), 256, 0, stream>>>(qkvr + 2048, vT, 4096);
  s2_direct<<<dim3(T_ / 32, H_), 256, 0, stream>>>(xb, wr, s2);

  // ---- branch 2 ----
  branch2_scan<<<dim3(H_, B_), 1024, 0, stream>>>(s2, qkvr + 3072, 4096, out2b);

  // ---- branch 3 ----
  a3_softmax<<<dim3(T_, B_), 256, 0, stream>>>(sc, a3p);
  gemm_bt<2,2,4,2,true><<<dim3(E_ / 64, T_ / 128, B_), 256, 0, stream>>>(
      a3p, echoT, out3b, E_, T_, T_, T_, E_,
      (long)T_ * T_, (long)E_ * T_, (long)T_ * E_, 1.f);

  // ---- branch 1: flash-fused ----
  flash1<<<dim3(T_ / 128, H_, B_), 256, 0, stream>>>(qkvr, vT, out1b);

  // ---- combine + output projection (128x64 tiles: 512 blocks) ----
  combine_gate<<<dim3((unsigned)(NTE / 256)), 256, 0, stream>>>(out1b, out2b, out3b, gate, comb);
  gemm_bt<2,2,4,2,false><<<dim3(E_ / 64, (B_ * T_) / 128, 1), 256, 0, stream>>>(
      comb, wob, out, E_, E_, E_, E_, E_, 0L, 0L, 0L, 1.f);
}